// Round 1
// baseline (1008.762 us; speedup 1.0000x reference)
//
#include <hip/hip_runtime.h>

// SAGEMeanConv: out = relu((scatter_sum(h_self[src], dst) + h_self) / (deg_dst + 1))
// h_self = feat @ W;  feat [100000,256] f32, W [256,128] f32, src/dst [1.6M] i32.
// d_out (12.8M f32) doubles as h_self scratch (finalize overwrites in place).
// d_ws: h_neigh (12.8M f32) + degs (100000 f32) = 51.6 MB.

#define IN_FEATS 256
#define OUT_FEATS 128
#define NUM_NODES 100000
#define NUM_EDGES 1600000

#define TM 64
#define TK 32

__global__ __launch_bounds__(256) void zero_ws_kernel(float4* __restrict__ p, int n4) {
    int i = blockIdx.x * 256 + threadIdx.x;
    if (i < n4) p[i] = make_float4(0.f, 0.f, 0.f, 0.f);
}

// hself[M,128] = feat[M,256] @ W[256,128]   (fp32, LDS-tiled, 8x4 per thread)
__global__ __launch_bounds__(256) void gemm_hself(
    const float* __restrict__ feat, const float* __restrict__ W,
    float* __restrict__ hself, int M)
{
    // +4 pad keeps lds_a[kk][row] rows 16B-aligned (stride 68 floats = 272 B)
    __shared__ float lds_a[TK][TM + 4];
    __shared__ float lds_b[TK][OUT_FEATS];

    const int tid = threadIdx.x;
    const int block_row = blockIdx.x * TM;
    const int tx = tid & 31;          // col group 0..31
    const int ty = tid >> 5;          // row group 0..7
    const int col0 = tx * 4;
    const int row0 = ty * 8;

    float acc[8][4];
#pragma unroll
    for (int r = 0; r < 8; ++r)
#pragma unroll
        for (int c = 0; c < 4; ++c) acc[r][c] = 0.f;

    const int ar = tid >> 2;          // A-stage row 0..63
    const int ak = (tid & 3) * 8;     // A-stage k base: 0,8,16,24

    for (int k0 = 0; k0 < IN_FEATS; k0 += TK) {
        // ---- stage A tile (transposed into LDS) ----
        float4 v0 = make_float4(0.f, 0.f, 0.f, 0.f), v1 = v0;
        int grow = block_row + ar;
        if (grow < M) {
            const float* p = feat + (size_t)grow * IN_FEATS + k0 + ak;
            v0 = *(const float4*)p;
            v1 = *(const float4*)(p + 4);
        }
        lds_a[ak + 0][ar] = v0.x; lds_a[ak + 1][ar] = v0.y;
        lds_a[ak + 2][ar] = v0.z; lds_a[ak + 3][ar] = v0.w;
        lds_a[ak + 4][ar] = v1.x; lds_a[ak + 5][ar] = v1.y;
        lds_a[ak + 6][ar] = v1.z; lds_a[ak + 7][ar] = v1.w;

        // ---- stage B tile (32 full rows of W are contiguous: 4096 floats) ----
        const float4* Bp = (const float4*)(W + (size_t)k0 * OUT_FEATS);
        float4* Lb = (float4*)lds_b;
#pragma unroll
        for (int j = 0; j < 4; ++j)
            Lb[tid + j * 256] = Bp[tid + j * 256];

        __syncthreads();

#pragma unroll
        for (int kk = 0; kk < TK; ++kk) {
            float4 b  = *(const float4*)&lds_b[kk][col0];
            float4 a0 = *(const float4*)&lds_a[kk][row0];
            float4 a1 = *(const float4*)&lds_a[kk][row0 + 4];
            float av[8] = { a0.x, a0.y, a0.z, a0.w, a1.x, a1.y, a1.z, a1.w };
            float bv[4] = { b.x, b.y, b.z, b.w };
#pragma unroll
            for (int r = 0; r < 8; ++r)
#pragma unroll
                for (int c = 0; c < 4; ++c)
                    acc[r][c] += av[r] * bv[c];
        }
        __syncthreads();
    }

#pragma unroll
    for (int r = 0; r < 8; ++r) {
        int grow = block_row + row0 + r;
        if (grow < M) {
            float4 o = make_float4(acc[r][0], acc[r][1], acc[r][2], acc[r][3]);
            *(float4*)&hself[(size_t)grow * OUT_FEATS + col0] = o;
        }
    }
}

// one thread per (edge, feat): h_neigh[dst][f] += h_self[src][f]; degs[dst] += 1 (f==0)
__global__ __launch_bounds__(256) void scatter_edges(
    const int* __restrict__ src, const int* __restrict__ dst,
    const float* __restrict__ hself, float* __restrict__ hneigh,
    float* __restrict__ degs)
{
    long long tid = (long long)blockIdx.x * 256 + threadIdx.x;
    int e = (int)(tid >> 7);
    int f = (int)(tid & 127);
    int s = src[e];
    int d = dst[e];
    atomicAdd(&hneigh[(size_t)d * OUT_FEATS + f], hself[(size_t)s * OUT_FEATS + f]);
    if (f == 0) atomicAdd(&degs[d], 1.0f);
}

// out = relu((h_neigh + h_self) / (deg + 1)), in place on d_out (holds h_self)
__global__ __launch_bounds__(256) void finalize_kernel(
    float4* __restrict__ out, const float4* __restrict__ hneigh,
    const float* __restrict__ degs)
{
    int i = blockIdx.x * 256 + threadIdx.x;       // float4 index, 3.2M total
    int n = i >> 5;                               // node = (i*4)/128
    float inv = 1.0f / (degs[n] + 1.0f);
    float4 hn = hneigh[i];
    float4 hs = out[i];
    float4 o;
    o.x = fmaxf((hn.x + hs.x) * inv, 0.f);
    o.y = fmaxf((hn.y + hs.y) * inv, 0.f);
    o.z = fmaxf((hn.z + hs.z) * inv, 0.f);
    o.w = fmaxf((hn.w + hs.w) * inv, 0.f);
    out[i] = o;
}

extern "C" void kernel_launch(void* const* d_in, const int* in_sizes, int n_in,
                              void* d_out, int out_size, void* d_ws, size_t ws_size,
                              hipStream_t stream) {
    const float* feat = (const float*)d_in[0];
    const float* W    = (const float*)d_in[1];
    const int*   src  = (const int*)d_in[2];
    const int*   dst  = (const int*)d_in[3];
    float* out    = (float*)d_out;
    float* hneigh = (float*)d_ws;
    float* degs   = hneigh + (size_t)NUM_NODES * OUT_FEATS;

    // zero h_neigh + degs (12,900,000 floats = 3,225,000 float4)
    int n4 = (NUM_NODES * OUT_FEATS + NUM_NODES) / 4;
    zero_ws_kernel<<<(n4 + 255) / 256, 256, 0, stream>>>((float4*)d_ws, n4);

    // h_self = feat @ W  -> d_out
    gemm_hself<<<(NUM_NODES + TM - 1) / TM, 256, 0, stream>>>(feat, W, out, NUM_NODES);

    // scatter-sum over edges: 1.6M * 128 threads = 204.8M, exactly 800000 blocks
    long long total = (long long)NUM_EDGES * OUT_FEATS;
    scatter_edges<<<(int)(total / 256), 256, 0, stream>>>(src, dst, out, hneigh, degs);

    // (h_neigh + h_self)/(deg+1), relu -> d_out (in place)
    int fn4 = NUM_NODES * OUT_FEATS / 4;          // 3,200,000 -> 12500 blocks
    finalize_kernel<<<fn4 / 256, 256, 0, stream>>>((float4*)out, (const float4*)hneigh, degs);
}

// Round 2
// 472.778 us; speedup vs baseline: 2.1337x; 2.1337x over previous
//
#include <hip/hip_runtime.h>
#include <hip/hip_bf16.h>

// SAGEMeanConv: out = relu((segment_sum(h_self[src], dst) + h_self) / (deg+1))
// h_self = feat @ W. CSR-based: histogram dst -> scan -> permute src -> gather.
// d_out holds fp32 h_self (self term), gather rewrites it in place (own row only).
// ws layout: hself_bf16[12.8M bf16] | counts[100k i32] | pos[100k i32] |
//            perm_src[1.6M i32] | offsets[100001 i32] | block_sums[98 i32]  (~33 MB)

#define IN_FEATS 256
#define OUT_FEATS 128
#define NUM_NODES 100000
#define NUM_EDGES 1600000

#define TM 64
#define TK 32

// ---------------- GEMM: h_self = feat @ W (fp32) + bf16 copy ----------------
__global__ __launch_bounds__(256) void gemm_hself(
    const float* __restrict__ feat, const float* __restrict__ W,
    float* __restrict__ hself, __hip_bfloat162* __restrict__ hself16, int M)
{
    __shared__ float lds_a[TK][TM + 4];
    __shared__ float lds_b[TK][OUT_FEATS];

    const int tid = threadIdx.x;
    const int block_row = blockIdx.x * TM;
    const int tx = tid & 31;
    const int ty = tid >> 5;
    const int col0 = tx * 4;
    const int row0 = ty * 8;

    float acc[8][4];
#pragma unroll
    for (int r = 0; r < 8; ++r)
#pragma unroll
        for (int c = 0; c < 4; ++c) acc[r][c] = 0.f;

    const int ar = tid >> 2;
    const int ak = (tid & 3) * 8;

    for (int k0 = 0; k0 < IN_FEATS; k0 += TK) {
        float4 v0 = make_float4(0.f, 0.f, 0.f, 0.f), v1 = v0;
        int grow = block_row + ar;
        if (grow < M) {
            const float* p = feat + (size_t)grow * IN_FEATS + k0 + ak;
            v0 = *(const float4*)p;
            v1 = *(const float4*)(p + 4);
        }
        lds_a[ak + 0][ar] = v0.x; lds_a[ak + 1][ar] = v0.y;
        lds_a[ak + 2][ar] = v0.z; lds_a[ak + 3][ar] = v0.w;
        lds_a[ak + 4][ar] = v1.x; lds_a[ak + 5][ar] = v1.y;
        lds_a[ak + 6][ar] = v1.z; lds_a[ak + 7][ar] = v1.w;

        const float4* Bp = (const float4*)(W + (size_t)k0 * OUT_FEATS);
        float4* Lb = (float4*)lds_b;
#pragma unroll
        for (int j = 0; j < 4; ++j)
            Lb[tid + j * 256] = Bp[tid + j * 256];

        __syncthreads();

#pragma unroll
        for (int kk = 0; kk < TK; ++kk) {
            float4 b  = *(const float4*)&lds_b[kk][col0];
            float4 a0 = *(const float4*)&lds_a[kk][row0];
            float4 a1 = *(const float4*)&lds_a[kk][row0 + 4];
            float av[8] = { a0.x, a0.y, a0.z, a0.w, a1.x, a1.y, a1.z, a1.w };
            float bv[4] = { b.x, b.y, b.z, b.w };
#pragma unroll
            for (int r = 0; r < 8; ++r)
#pragma unroll
                for (int c = 0; c < 4; ++c)
                    acc[r][c] += av[r] * bv[c];
        }
        __syncthreads();
    }

#pragma unroll
    for (int r = 0; r < 8; ++r) {
        int grow = block_row + row0 + r;
        if (grow < M) {
            float4 o = make_float4(acc[r][0], acc[r][1], acc[r][2], acc[r][3]);
            *(float4*)&hself[(size_t)grow * OUT_FEATS + col0] = o;
            __hip_bfloat162 p0, p1;
            p0.x = __float2bfloat16(o.x); p0.y = __float2bfloat16(o.y);
            p1.x = __float2bfloat16(o.z); p1.y = __float2bfloat16(o.w);
            size_t h16i = (size_t)grow * (OUT_FEATS / 2) + (col0 >> 1);
            hself16[h16i]     = p0;
            hself16[h16i + 1] = p1;
        }
    }
}

// ---------------- degree histogram ----------------
__global__ __launch_bounds__(256) void hist_kernel(
    const int* __restrict__ dst, int* __restrict__ counts)
{
    int e = blockIdx.x * 256 + threadIdx.x;
    if (e < NUM_EDGES) atomicAdd(&counts[dst[e]], 1);
}

// ---------------- exclusive scan (3 kernels, 1024 elems/block) ----------------
__global__ __launch_bounds__(256) void scan1_kernel(
    const int* __restrict__ counts, int* __restrict__ offsets,
    int* __restrict__ block_sums)
{
    __shared__ int sd[256];
    int t = threadIdx.x;
    int base = blockIdx.x * 1024 + t * 4;
    int v0 = 0, v1 = 0, v2 = 0, v3 = 0;
    if (base + 3 < NUM_NODES) {
        int4 v = *(const int4*)&counts[base];
        v0 = v.x; v1 = v.y; v2 = v.z; v3 = v.w;
    } else {
        if (base + 0 < NUM_NODES) v0 = counts[base + 0];
        if (base + 1 < NUM_NODES) v1 = counts[base + 1];
        if (base + 2 < NUM_NODES) v2 = counts[base + 2];
        if (base + 3 < NUM_NODES) v3 = counts[base + 3];
    }
    int s = v0 + v1 + v2 + v3;
    sd[t] = s;
    __syncthreads();
    for (int off = 1; off < 256; off <<= 1) {
        int x = (t >= off) ? sd[t - off] : 0;
        __syncthreads();
        sd[t] += x;
        __syncthreads();
    }
    int excl = sd[t] - s;
    if (t == 255) block_sums[blockIdx.x] = sd[255];
    int e0 = excl, e1 = e0 + v0, e2 = e1 + v1, e3 = e2 + v2;
    if (base + 3 < NUM_NODES) {
        *(int4*)&offsets[base] = make_int4(e0, e1, e2, e3);
    } else {
        if (base + 0 < NUM_NODES) offsets[base + 0] = e0;
        if (base + 1 < NUM_NODES) offsets[base + 1] = e1;
        if (base + 2 < NUM_NODES) offsets[base + 2] = e2;
        if (base + 3 < NUM_NODES) offsets[base + 3] = e3;
    }
}

__global__ __launch_bounds__(128) void scan2_kernel(int* __restrict__ block_sums, int nblk)
{
    __shared__ int sd[128];
    int t = threadIdx.x;
    int v = (t < nblk) ? block_sums[t] : 0;
    sd[t] = v;
    __syncthreads();
    for (int off = 1; off < 128; off <<= 1) {
        int x = (t >= off) ? sd[t - off] : 0;
        __syncthreads();
        sd[t] += x;
        __syncthreads();
    }
    if (t < nblk) block_sums[t] = sd[t] - v;   // exclusive
}

__global__ __launch_bounds__(256) void scan3_kernel(
    int* __restrict__ offsets, const int* __restrict__ block_sums)
{
    int i = blockIdx.x * 256 + threadIdx.x;
    if (i < NUM_NODES) offsets[i] += block_sums[i >> 10];
    if (i == 0) offsets[NUM_NODES] = NUM_EDGES;
}

// ---------------- fill permuted src (counting-sort scatter) ----------------
__global__ __launch_bounds__(256) void fill_perm_kernel(
    const int* __restrict__ src, const int* __restrict__ dst,
    const int* __restrict__ offsets, int* __restrict__ pos,
    int* __restrict__ perm_src)
{
    int e = blockIdx.x * 256 + threadIdx.x;
    if (e < NUM_EDGES) {
        int d = dst[e];
        int p = atomicAdd(&pos[d], 1);
        perm_src[offsets[d] + p] = src[e];
    }
}

// ---------------- gather + finalize (fused) ----------------
// 4 nodes per block (4 waves); lane handles feats 2l, 2l+1 via bf16x2.
__global__ __launch_bounds__(256) void gather_finalize(
    const int* __restrict__ offsets, const int* __restrict__ perm_src,
    const __hip_bfloat162* __restrict__ hself16, float* __restrict__ out)
{
    int n = blockIdx.x * 4 + (threadIdx.x >> 6);
    int l = threadIdx.x & 63;
    int beg = offsets[n];
    int end = offsets[n + 1];
    size_t si = (size_t)n * 64 + l;
    float2 selfv = ((const float2*)out)[si];
    float acc0 = selfv.x, acc1 = selfv.y;
    int j = beg;
    for (; j + 1 < end; j += 2) {
        int s0 = perm_src[j];
        int s1 = perm_src[j + 1];
        __hip_bfloat162 h0 = hself16[(size_t)s0 * 64 + l];
        __hip_bfloat162 h1 = hself16[(size_t)s1 * 64 + l];
        acc0 += __bfloat162float(h0.x) + __bfloat162float(h1.x);
        acc1 += __bfloat162float(h0.y) + __bfloat162float(h1.y);
    }
    if (j < end) {
        int s0 = perm_src[j];
        __hip_bfloat162 h0 = hself16[(size_t)s0 * 64 + l];
        acc0 += __bfloat162float(h0.x);
        acc1 += __bfloat162float(h0.y);
    }
    float inv = 1.0f / (float)(end - beg + 1);
    float2 o;
    o.x = fmaxf(acc0 * inv, 0.f);
    o.y = fmaxf(acc1 * inv, 0.f);
    ((float2*)out)[si] = o;
}

extern "C" void kernel_launch(void* const* d_in, const int* in_sizes, int n_in,
                              void* d_out, int out_size, void* d_ws, size_t ws_size,
                              hipStream_t stream) {
    const float* feat = (const float*)d_in[0];
    const float* W    = (const float*)d_in[1];
    const int*   src  = (const int*)d_in[2];
    const int*   dst  = (const int*)d_in[3];
    float* out = (float*)d_out;

    char* ws = (char*)d_ws;
    __hip_bfloat162* hself16 = (__hip_bfloat162*)ws;              // 25,600,000 B
    int* counts     = (int*)(ws + 25600000);                      //    400,000 B
    int* pos        = (int*)(ws + 26000000);                      //    400,000 B
    int* perm_src   = (int*)(ws + 26400000);                      //  6,400,000 B
    int* offsets    = (int*)(ws + 32800000);                      //    400,004 B
    int* block_sums = (int*)(ws + 33200016);                      //        392 B

    // zero counts + pos (adjacent, 800 KB)
    hipMemsetAsync(counts, 0, 800000, stream);

    // h_self = feat @ W -> d_out (fp32) + ws (bf16)
    gemm_hself<<<(NUM_NODES + TM - 1) / TM, 256, 0, stream>>>(feat, W, out, hself16, NUM_NODES);

    // CSR build
    hist_kernel<<<NUM_EDGES / 256, 256, 0, stream>>>(dst, counts);
    scan1_kernel<<<(NUM_NODES + 1023) / 1024, 256, 0, stream>>>(counts, offsets, block_sums);
    scan2_kernel<<<1, 128, 0, stream>>>(block_sums, (NUM_NODES + 1023) / 1024);
    scan3_kernel<<<(NUM_NODES + 255) / 256, 256, 0, stream>>>(offsets, block_sums);
    fill_perm_kernel<<<NUM_EDGES / 256, 256, 0, stream>>>(src, dst, offsets, pos, perm_src);

    // gather + finalize (4 nodes per 256-thread block)
    gather_finalize<<<NUM_NODES / 4, 256, 0, stream>>>(offsets, perm_src, hself16, out);
}

// Round 3
// 407.479 us; speedup vs baseline: 2.4756x; 1.1603x over previous
//
#include <hip/hip_runtime.h>

// SAGEMeanConv: out = relu((segment_sum(h_self[src], dst) + h_self) / (deg+1))
// h_self = feat @ W via bf16 MFMA (fp32 accumulate). CSR gather (no fp32 atomics).
// d_out: final output only. ws: hself_bf16 | Wt_bf16 | counts | pos | perm_src |
// offsets | block_sums  (~33.3 MB).

#define IN_FEATS 256
#define OUT_FEATS 128
#define NUM_NODES 100000
#define NUM_EDGES 1600000

typedef __attribute__((ext_vector_type(8))) short short8;
typedef __attribute__((ext_vector_type(8))) unsigned short ushort8;
typedef __attribute__((ext_vector_type(4))) float f32x4;

#define LDA 72   // padded bf16 row stride in LDS (64 + 8): breaks 128B-stride conflicts

static __device__ inline unsigned short f2bf(float x) {
    unsigned u = __float_as_uint(x);
    unsigned r = u + 0x7FFF + ((u >> 16) & 1);   // round-to-nearest-even
    return (unsigned short)(r >> 16);
}
static __device__ inline float bf2f(unsigned short h) {
    return __uint_as_float((unsigned)h << 16);
}

// ---------------- Wt[n][k] = bf16(W[k][n]) ----------------
__global__ __launch_bounds__(256) void convert_wt(
    const float* __restrict__ W, unsigned short* __restrict__ Wt)
{
    int i = blockIdx.x * 256 + threadIdx.x;   // 32768 = 128n x 256k
    int n = i >> 8;
    int k = i & 255;
    Wt[i] = f2bf(W[(size_t)k * OUT_FEATS + n]);
}

// ---------------- h_self(bf16) = feat @ W, MFMA 16x16x32 ----------------
__global__ __launch_bounds__(256) void gemm_mfma(
    const float* __restrict__ feat, const unsigned short* __restrict__ Wt,
    unsigned short* __restrict__ hself16, int M)
{
    __shared__ short smem[2 * 128 * LDA];     // 36,864 B
    short* a_lds = smem;                      // A: [128 m][LDA k]
    short* b_lds = smem + 128 * LDA;          // B: [128 n][LDA k]

    const int tid = threadIdx.x;
    const int w  = tid >> 6;
    const int l  = tid & 63;
    const int lf = l & 15;
    const int lg = l >> 4;
    const int wm = (w & 1) * 64;
    const int wn = (w >> 1) * 64;
    const int bm0 = blockIdx.x * 128;

    f32x4 acc[4][4];
#pragma unroll
    for (int mt = 0; mt < 4; ++mt)
#pragma unroll
        for (int nt = 0; nt < 4; ++nt)
            acc[mt][nt] = (f32x4){0.f, 0.f, 0.f, 0.f};

    const int srow  = tid >> 1;               // 0..127
    const int skseg = (tid & 1) * 32;         // 0 or 32

    for (int k0 = 0; k0 < IN_FEATS; k0 += 64) {
        // ---- stage A: fp32 feat -> bf16 LDS (inline convert) ----
        int grow = bm0 + srow;
        unsigned short hv[32];
        if (grow < M) {
            const float4* gp = (const float4*)(feat + (size_t)grow * IN_FEATS + k0 + skseg);
#pragma unroll
            for (int i = 0; i < 8; ++i) {
                float4 v = gp[i];
                hv[i * 4 + 0] = f2bf(v.x);
                hv[i * 4 + 1] = f2bf(v.y);
                hv[i * 4 + 2] = f2bf(v.z);
                hv[i * 4 + 3] = f2bf(v.w);
            }
        } else {
#pragma unroll
            for (int i = 0; i < 32; ++i) hv[i] = 0;
        }
        {
            ushort8* ap = (ushort8*)(a_lds + srow * LDA + skseg);
#pragma unroll
            for (int i = 0; i < 4; ++i) {
                ushort8 p;
#pragma unroll
                for (int j = 0; j < 8; ++j) p[j] = hv[i * 8 + j];
                ap[i] = p;
            }
        }
        // ---- stage B: Wt bf16 -> LDS (copy) ----
        {
            const ushort8* wp = (const ushort8*)(Wt + (size_t)srow * IN_FEATS + k0 + skseg);
            ushort8* bp = (ushort8*)(b_lds + srow * LDA + skseg);
#pragma unroll
            for (int i = 0; i < 4; ++i) bp[i] = wp[i];
        }
        __syncthreads();

#pragma unroll
        for (int ks = 0; ks < 64; ks += 32) {
            short8 af[4], bfr[4];
#pragma unroll
            for (int mt = 0; mt < 4; ++mt)
                af[mt] = *(const short8*)(a_lds + (wm + mt * 16 + lf) * LDA + ks + lg * 8);
#pragma unroll
            for (int nt = 0; nt < 4; ++nt)
                bfr[nt] = *(const short8*)(b_lds + (wn + nt * 16 + lf) * LDA + ks + lg * 8);
#pragma unroll
            for (int mt = 0; mt < 4; ++mt)
#pragma unroll
                for (int nt = 0; nt < 4; ++nt)
                    acc[mt][nt] = __builtin_amdgcn_mfma_f32_16x16x32_bf16(
                        af[mt], bfr[nt], acc[mt][nt], 0, 0, 0);
        }
        __syncthreads();
    }

    // ---- epilogue: LDS transpose -> coalesced bf16 stores ----
    // wave-private region: 64 rows x LDA, 9216 B each, 4 waves = 36,864 B exactly
    short* ep = smem + w * (64 * LDA);
#pragma unroll
    for (int mt = 0; mt < 4; ++mt)
#pragma unroll
        for (int nt = 0; nt < 4; ++nt)
#pragma unroll
            for (int r = 0; r < 4; ++r)
                ep[(mt * 16 + lg * 4 + r) * LDA + nt * 16 + lf] =
                    (short)f2bf(acc[mt][nt][r]);
    // own-wave write->read, ordered by lgkmcnt; regions disjoint across waves
#pragma unroll
    for (int rr = 0; rr < 8; ++rr) {
        int row = rr * 8 + (l >> 3);
        short8 v = *(const short8*)(ep + row * LDA + (l & 7) * 8);
        int grow = bm0 + wm + row;
        if (grow < M)
            *(short8*)(hself16 + (size_t)grow * OUT_FEATS + wn + (l & 7) * 8) = v;
    }
}

// ---------------- degree histogram ----------------
__global__ __launch_bounds__(256) void hist_kernel(
    const int* __restrict__ dst, int* __restrict__ counts)
{
    int e = blockIdx.x * 256 + threadIdx.x;
    if (e < NUM_EDGES) atomicAdd(&counts[dst[e]], 1);
}

// ---------------- scan: per-1024-chunk exclusive + chunk sums ----------------
__global__ __launch_bounds__(256) void scan1_kernel(
    const int* __restrict__ counts, int* __restrict__ offsets,
    int* __restrict__ block_sums)
{
    __shared__ int sd[256];
    int t = threadIdx.x;
    int base = blockIdx.x * 1024 + t * 4;
    int v0 = 0, v1 = 0, v2 = 0, v3 = 0;
    if (base + 3 < NUM_NODES) {
        int4 v = *(const int4*)&counts[base];
        v0 = v.x; v1 = v.y; v2 = v.z; v3 = v.w;
    } else {
        if (base + 0 < NUM_NODES) v0 = counts[base + 0];
        if (base + 1 < NUM_NODES) v1 = counts[base + 1];
        if (base + 2 < NUM_NODES) v2 = counts[base + 2];
        if (base + 3 < NUM_NODES) v3 = counts[base + 3];
    }
    int s = v0 + v1 + v2 + v3;
    sd[t] = s;
    __syncthreads();
    for (int off = 1; off < 256; off <<= 1) {
        int x = (t >= off) ? sd[t - off] : 0;
        __syncthreads();
        sd[t] += x;
        __syncthreads();
    }
    int excl = sd[t] - s;
    if (t == 255) block_sums[blockIdx.x] = sd[255];
    int e0 = excl, e1 = e0 + v0, e2 = e1 + v1, e3 = e2 + v2;
    if (base + 3 < NUM_NODES) {
        *(int4*)&offsets[base] = make_int4(e0, e1, e2, e3);
    } else {
        if (base + 0 < NUM_NODES) offsets[base + 0] = e0;
        if (base + 1 < NUM_NODES) offsets[base + 1] = e1;
        if (base + 2 < NUM_NODES) offsets[base + 2] = e2;
        if (base + 3 < NUM_NODES) offsets[base + 3] = e3;
    }
}

__global__ __launch_bounds__(128) void scan2_kernel(int* __restrict__ block_sums, int nblk)
{
    __shared__ int sd[128];
    int t = threadIdx.x;
    int v = (t < nblk) ? block_sums[t] : 0;
    sd[t] = v;
    __syncthreads();
    for (int off = 1; off < 128; off <<= 1) {
        int x = (t >= off) ? sd[t - off] : 0;
        __syncthreads();
        sd[t] += x;
        __syncthreads();
    }
    if (t < nblk) block_sums[t] = sd[t] - v;   // exclusive over chunks
}

// ---------------- fill permuted src (bsums folded in) ----------------
__global__ __launch_bounds__(256) void fill_perm_kernel(
    const int* __restrict__ src, const int* __restrict__ dst,
    const int* __restrict__ offsets, const int* __restrict__ block_sums,
    int* __restrict__ pos, int* __restrict__ perm_src)
{
    int e = blockIdx.x * 256 + threadIdx.x;
    if (e < NUM_EDGES) {
        int d = dst[e];
        int p = atomicAdd(&pos[d], 1);
        perm_src[offsets[d] + block_sums[d >> 10] + p] = src[e];
    }
}

// ---------------- gather + finalize: 1 node/wave, 4 src rows in flight ----------------
__global__ __launch_bounds__(256) void gather_finalize(
    const int* __restrict__ offsets, const int* __restrict__ block_sums,
    const int* __restrict__ perm_src, const unsigned short* __restrict__ hself16,
    float* __restrict__ out)
{
    int n = blockIdx.x * 4 + (threadIdx.x >> 6);
    int l = threadIdx.x & 63;
    int lg = l >> 4;                   // source-row group 0..3
    int lf = l & 15;                   // feats lf*8 .. lf*8+7
    int beg = offsets[n] + block_sums[n >> 10];
    int end = (n == NUM_NODES - 1) ? NUM_EDGES
                                   : offsets[n + 1] + block_sums[(n + 1) >> 10];
    float acc[8];
#pragma unroll
    for (int i = 0; i < 8; ++i) acc[i] = 0.f;

    for (int j0 = beg; j0 < end; j0 += 4) {
        int j = j0 + lg;
        if (j < end) {
            int s = perm_src[j];
            ushort8 h = *(const ushort8*)(hself16 + (size_t)s * OUT_FEATS + lf * 8);
#pragma unroll
            for (int i = 0; i < 8; ++i) acc[i] += bf2f(h[i]);
        }
    }
#pragma unroll
    for (int i = 0; i < 8; ++i) {
        acc[i] += __shfl_xor(acc[i], 16, 64);
        acc[i] += __shfl_xor(acc[i], 32, 64);
    }
    if (lg == 0) {
        float inv = 1.0f / (float)(end - beg + 1);
        ushort8 hs = *(const ushort8*)(hself16 + (size_t)n * OUT_FEATS + lf * 8);
        float v[8];
#pragma unroll
        for (int i = 0; i < 8; ++i)
            v[i] = fmaxf((acc[i] + bf2f(hs[i])) * inv, 0.f);
        float4* op = (float4*)(out + (size_t)n * OUT_FEATS + lf * 8);
        op[0] = make_float4(v[0], v[1], v[2], v[3]);
        op[1] = make_float4(v[4], v[5], v[6], v[7]);
    }
}

extern "C" void kernel_launch(void* const* d_in, const int* in_sizes, int n_in,
                              void* d_out, int out_size, void* d_ws, size_t ws_size,
                              hipStream_t stream) {
    const float* feat = (const float*)d_in[0];
    const float* W    = (const float*)d_in[1];
    const int*   src  = (const int*)d_in[2];
    const int*   dst  = (const int*)d_in[3];
    float* out = (float*)d_out;

    char* ws = (char*)d_ws;
    unsigned short* hself16 = (unsigned short*)ws;                 // 25,600,000 B
    unsigned short* Wt      = (unsigned short*)(ws + 25600000);    //     65,536 B
    int* counts     = (int*)(ws + 25665536);                       //    400,000 B
    int* pos        = (int*)(ws + 26065536);                       //    400,000 B
    int* perm_src   = (int*)(ws + 26465536);                       //  6,400,000 B
    int* offsets    = (int*)(ws + 32865536);                       //    400,000 B
    int* block_sums = (int*)(ws + 33265536);                       //        512 B

    hipMemsetAsync(counts, 0, 800000, stream);   // counts + pos (adjacent)

    convert_wt<<<128, 256, 0, stream>>>(W, Wt);
    gemm_mfma<<<(NUM_NODES + 127) / 128, 256, 0, stream>>>(feat, Wt, hself16, NUM_NODES);

    hist_kernel<<<NUM_EDGES / 256, 256, 0, stream>>>(dst, counts);
    scan1_kernel<<<(NUM_NODES + 1023) / 1024, 256, 0, stream>>>(counts, offsets, block_sums);
    scan2_kernel<<<1, 128, 0, stream>>>(block_sums, (NUM_NODES + 1023) / 1024);
    fill_perm_kernel<<<NUM_EDGES / 256, 256, 0, stream>>>(src, dst, offsets, block_sums, pos, perm_src);

    gather_finalize<<<NUM_NODES / 4, 256, 0, stream>>>(offsets, block_sums, perm_src, hself16, out);
}

// Round 4
// 390.547 us; speedup vs baseline: 2.5829x; 1.0434x over previous
//
#include <hip/hip_runtime.h>
#include <hip/hip_bf16.h>

// SAGEMeanConv: out = relu((segment_sum(h_self[src], dst) + h_self) / (deg+1))
// h_self = feat @ W via bf16 MFMA. CSR gather. Round 4:
//  - fill scatter is range-localized (8 dst ranges, ~800KB perm window each -> L2)
//  - convert_wt fused with hist; gemm fused with fill (independent, block-partitioned)
//  - gather keeps 8 source rows in flight; packed bf16 cvt in gemm

#define IN_FEATS 256
#define OUT_FEATS 128
#define NUM_NODES 100000
#define NUM_EDGES 1600000

#define NR 8                 // dst ranges for fill locality
#define RANGE_NODES 12500    // NUM_NODES / NR
#define FILL_CHUNK 2048      // edges per fill block
#define NCHUNK 782           // ceil(NUM_EDGES / FILL_CHUNK)
#define GEMM_BLOCKS 782      // ceil(100000 / 128)

typedef __attribute__((ext_vector_type(8))) short short8;
typedef __attribute__((ext_vector_type(8))) unsigned short ushort8;
typedef __attribute__((ext_vector_type(4))) float f32x4;

#define LDA 72   // padded bf16 row stride in LDS

static __device__ inline unsigned short f2bfu(float x) {
    union { __hip_bfloat16 h; unsigned short u; } c;
    c.h = __float2bfloat16(x);
    return c.u;
}
static __device__ inline ushort2 f2bfu2(float x, float y) {
    union { __hip_bfloat162 h; ushort2 u; } c;
    c.h = __float22bfloat162_rn(make_float2(x, y));
    return c.u;
}
static __device__ inline float bf2f(unsigned short h) {
    return __uint_as_float((unsigned)h << 16);
}

// ---------------- K1: convert_wt (blocks 0..127) U hist (blocks 128..6377) ----------------
__global__ __launch_bounds__(256) void convert_hist(
    const float* __restrict__ W, unsigned short* __restrict__ Wt,
    const int* __restrict__ dst, int* __restrict__ counts)
{
    int b = blockIdx.x;
    if (b < 128) {
        int i = b * 256 + threadIdx.x;   // 32768 = 128n x 256k
        int n = i >> 8;
        int k = i & 255;
        Wt[i] = f2bfu(W[(size_t)k * OUT_FEATS + n]);
    } else {
        int e = (b - 128) * 256 + threadIdx.x;   // 6250 blocks x 256 = 1.6M exact
        atomicAdd(&counts[dst[e]], 1);
    }
}

// ---------------- scan: per-1024-chunk exclusive + chunk sums ----------------
__global__ __launch_bounds__(256) void scan1_kernel(
    const int* __restrict__ counts, int* __restrict__ offsets,
    int* __restrict__ block_sums)
{
    __shared__ int sd[256];
    int t = threadIdx.x;
    int base = blockIdx.x * 1024 + t * 4;
    int v0 = 0, v1 = 0, v2 = 0, v3 = 0;
    if (base + 3 < NUM_NODES) {
        int4 v = *(const int4*)&counts[base];
        v0 = v.x; v1 = v.y; v2 = v.z; v3 = v.w;
    } else {
        if (base + 0 < NUM_NODES) v0 = counts[base + 0];
        if (base + 1 < NUM_NODES) v1 = counts[base + 1];
        if (base + 2 < NUM_NODES) v2 = counts[base + 2];
        if (base + 3 < NUM_NODES) v3 = counts[base + 3];
    }
    int s = v0 + v1 + v2 + v3;
    sd[t] = s;
    __syncthreads();
    for (int off = 1; off < 256; off <<= 1) {
        int x = (t >= off) ? sd[t - off] : 0;
        __syncthreads();
        sd[t] += x;
        __syncthreads();
    }
    int excl = sd[t] - s;
    if (t == 255) block_sums[blockIdx.x] = sd[255];
    int e0 = excl, e1 = e0 + v0, e2 = e1 + v1, e3 = e2 + v2;
    if (base + 3 < NUM_NODES) {
        *(int4*)&offsets[base] = make_int4(e0, e1, e2, e3);
    } else {
        if (base + 0 < NUM_NODES) offsets[base + 0] = e0;
        if (base + 1 < NUM_NODES) offsets[base + 1] = e1;
        if (base + 2 < NUM_NODES) offsets[base + 2] = e2;
        if (base + 3 < NUM_NODES) offsets[base + 3] = e3;
    }
}

__global__ __launch_bounds__(128) void scan2_kernel(int* __restrict__ block_sums, int nblk)
{
    __shared__ int sd[128];
    int t = threadIdx.x;
    int v = (t < nblk) ? block_sums[t] : 0;
    sd[t] = v;
    __syncthreads();
    for (int off = 1; off < 128; off <<= 1) {
        int x = (t >= off) ? sd[t - off] : 0;
        __syncthreads();
        sd[t] += x;
        __syncthreads();
    }
    if (t < nblk) block_sums[t] = sd[t] - v;   // exclusive over chunks
}

// ---------------- K3: gemm (blocks 0..781) U range-localized fill (rest) ----------------
__global__ __launch_bounds__(256) void gemm_fill(
    const float* __restrict__ feat, const unsigned short* __restrict__ Wt,
    unsigned short* __restrict__ hself16, int M,
    const int* __restrict__ src, const int* __restrict__ dst,
    const int* __restrict__ offsets, const int* __restrict__ block_sums,
    int* __restrict__ pos, int* __restrict__ perm_src)
{
    __shared__ short smem[2 * 128 * LDA];     // 36,864 B (gemm path only)

    if (blockIdx.x >= GEMM_BLOCKS) {
        // ---------------- fill path ----------------
        int b = blockIdx.x - GEMM_BLOCKS;
        int r = b / NCHUNK;                   // dst range, advances slowly with block ID
        int c = b % NCHUNK;                   // edge chunk
        int lo = r * RANGE_NODES;
        int hi = lo + RANGE_NODES;
        int t = threadIdx.x;
#pragma unroll
        for (int seg = 0; seg < 2; ++seg) {
            int e0 = c * FILL_CHUNK + seg * 1024 + t * 4;
            if (e0 < NUM_EDGES) {
                int4 d4 = *(const int4*)&dst[e0];
                int4 s4 = *(const int4*)&src[e0];
                int dv[4] = { d4.x, d4.y, d4.z, d4.w };
                int sv[4] = { s4.x, s4.y, s4.z, s4.w };
#pragma unroll
                for (int i = 0; i < 4; ++i) {
                    int d = dv[i];
                    if (d >= lo && d < hi) {
                        int p = atomicAdd(&pos[d], 1);
                        perm_src[offsets[d] + block_sums[d >> 10] + p] = sv[i];
                    }
                }
            }
        }
        return;
    }

    // ---------------- gemm path ----------------
    short* a_lds = smem;                      // A: [128 m][LDA k]
    short* b_lds = smem + 128 * LDA;          // B: [128 n][LDA k]

    const int tid = threadIdx.x;
    const int w  = tid >> 6;
    const int l  = tid & 63;
    const int lf = l & 15;
    const int lg = l >> 4;
    const int wm = (w & 1) * 64;
    const int wn = (w >> 1) * 64;
    const int bm0 = blockIdx.x * 128;

    f32x4 acc[4][4];
#pragma unroll
    for (int mt = 0; mt < 4; ++mt)
#pragma unroll
        for (int nt = 0; nt < 4; ++nt)
            acc[mt][nt] = (f32x4){0.f, 0.f, 0.f, 0.f};

    const int srow  = tid >> 1;               // 0..127
    const int skseg = (tid & 1) * 32;         // 0 or 32

    for (int k0 = 0; k0 < IN_FEATS; k0 += 64) {
        // ---- stage A: fp32 feat -> bf16 LDS (packed cvt) ----
        int grow = bm0 + srow;
        ushort8* ap = (ushort8*)(a_lds + srow * LDA + skseg);
        if (grow < M) {
            const float4* gp = (const float4*)(feat + (size_t)grow * IN_FEATS + k0 + skseg);
#pragma unroll
            for (int i = 0; i < 4; ++i) {
                float4 v0 = gp[2 * i];
                float4 v1 = gp[2 * i + 1];
                ushort2 c0 = f2bfu2(v0.x, v0.y);
                ushort2 c1 = f2bfu2(v0.z, v0.w);
                ushort2 c2 = f2bfu2(v1.x, v1.y);
                ushort2 c3 = f2bfu2(v1.z, v1.w);
                ushort8 p = { c0.x, c0.y, c1.x, c1.y, c2.x, c2.y, c3.x, c3.y };
                ap[i] = p;
            }
        } else {
            ushort8 z = { 0, 0, 0, 0, 0, 0, 0, 0 };
#pragma unroll
            for (int i = 0; i < 4; ++i) ap[i] = z;
        }
        // ---- stage B: Wt bf16 -> LDS ----
        {
            const ushort8* wp = (const ushort8*)(Wt + (size_t)srow * IN_FEATS + k0 + skseg);
            ushort8* bp = (ushort8*)(b_lds + srow * LDA + skseg);
#pragma unroll
            for (int i = 0; i < 4; ++i) bp[i] = wp[i];
        }
        __syncthreads();

#pragma unroll
        for (int ks = 0; ks < 64; ks += 32) {
            short8 af[4], bfr[4];
#pragma unroll
            for (int mt = 0; mt < 4; ++mt)
                af[mt] = *(const short8*)(a_lds + (wm + mt * 16 + lf) * LDA + ks + lg * 8);
#pragma unroll
            for (int nt = 0; nt < 4; ++nt)
                bfr[nt] = *(const short8*)(b_lds + (wn + nt * 16 + lf) * LDA + ks + lg * 8);
#pragma unroll
            for (int mt = 0; mt < 4; ++mt)
#pragma unroll
                for (int nt = 0; nt < 4; ++nt)
                    acc[mt][nt] = __builtin_amdgcn_mfma_f32_16x16x32_bf16(
                        af[mt], bfr[nt], acc[mt][nt], 0, 0, 0);
        }
        __syncthreads();
    }

    // ---- epilogue: LDS transpose -> coalesced bf16 stores ----
    short* ep = smem + w * (64 * LDA);        // wave-private 9216 B region
#pragma unroll
    for (int mt = 0; mt < 4; ++mt)
#pragma unroll
        for (int nt = 0; nt < 4; ++nt)
#pragma unroll
            for (int r = 0; r < 4; r += 2) {
                ushort2 cv = f2bfu2(acc[mt][nt][r], acc[mt][nt][r + 1]);
                ep[(mt * 16 + lg * 4 + r) * LDA + nt * 16 + lf]     = (short)cv.x;
                ep[(mt * 16 + lg * 4 + r + 1) * LDA + nt * 16 + lf] = (short)cv.y;
            }
#pragma unroll
    for (int rr = 0; rr < 8; ++rr) {
        int row = rr * 8 + (l >> 3);
        short8 v = *(const short8*)(ep + row * LDA + (l & 7) * 8);
        int grow = bm0 + wm + row;
        if (grow < M)
            *(short8*)(hself16 + (size_t)grow * OUT_FEATS + wn + (l & 7) * 8) = v;
    }
}

// ---------------- gather + finalize: 1 node/wave, 8 src rows in flight ----------------
__global__ __launch_bounds__(256) void gather_finalize(
    const int* __restrict__ offsets, const int* __restrict__ block_sums,
    const int* __restrict__ perm_src, const unsigned short* __restrict__ hself16,
    float* __restrict__ out)
{
    int n = blockIdx.x * 4 + (threadIdx.x >> 6);
    int l = threadIdx.x & 63;
    int lg = l >> 4;                   // source-row group 0..3
    int lf = l & 15;                   // feats lf*8 .. lf*8+7
    int beg = offsets[n] + block_sums[n >> 10];
    int end = (n == NUM_NODES - 1) ? NUM_EDGES
                                   : offsets[n + 1] + block_sums[(n + 1) >> 10];
    float acc[8];
#pragma unroll
    for (int i = 0; i < 8; ++i) acc[i] = 0.f;

    for (int j0 = beg; j0 < end; j0 += 8) {
        int ja = j0 + lg;
        int jb = j0 + 4 + lg;
        bool pa = ja < end;
        bool pb = jb < end;
        int sa = pa ? perm_src[ja] : 0;
        int sb = pb ? perm_src[jb] : 0;
        ushort8 ha = *(const ushort8*)(hself16 + (size_t)sa * OUT_FEATS + lf * 8);
        ushort8 hb = *(const ushort8*)(hself16 + (size_t)sb * OUT_FEATS + lf * 8);
        if (pa) {
#pragma unroll
            for (int i = 0; i < 8; ++i) acc[i] += bf2f(ha[i]);
        }
        if (pb) {
#pragma unroll
            for (int i = 0; i < 8; ++i) acc[i] += bf2f(hb[i]);
        }
    }
#pragma unroll
    for (int i = 0; i < 8; ++i) {
        acc[i] += __shfl_xor(acc[i], 16, 64);
        acc[i] += __shfl_xor(acc[i], 32, 64);
    }
    if (lg == 0) {
        float inv = 1.0f / (float)(end - beg + 1);
        ushort8 hs = *(const ushort8*)(hself16 + (size_t)n * OUT_FEATS + lf * 8);
        float v[8];
#pragma unroll
        for (int i = 0; i < 8; ++i)
            v[i] = fmaxf((acc[i] + bf2f(hs[i])) * inv, 0.f);
        float4* op = (float4*)(out + (size_t)n * OUT_FEATS + lf * 8);
        op[0] = make_float4(v[0], v[1], v[2], v[3]);
        op[1] = make_float4(v[4], v[5], v[6], v[7]);
    }
}

extern "C" void kernel_launch(void* const* d_in, const int* in_sizes, int n_in,
                              void* d_out, int out_size, void* d_ws, size_t ws_size,
                              hipStream_t stream) {
    const float* feat = (const float*)d_in[0];
    const float* W    = (const float*)d_in[1];
    const int*   src  = (const int*)d_in[2];
    const int*   dst  = (const int*)d_in[3];
    float* out = (float*)d_out;

    char* ws = (char*)d_ws;
    unsigned short* hself16 = (unsigned short*)ws;                 // 25,600,000 B
    unsigned short* Wt      = (unsigned short*)(ws + 25600000);    //     65,536 B
    int* counts     = (int*)(ws + 25665536);                       //    400,000 B
    int* pos        = (int*)(ws + 26065536);                       //    400,000 B
    int* perm_src   = (int*)(ws + 26465536);                       //  6,400,000 B
    int* offsets    = (int*)(ws + 32865536);                       //    400,000 B
    int* block_sums = (int*)(ws + 33265536);                       //        512 B

    hipMemsetAsync(counts, 0, 800000, stream);   // counts + pos (adjacent)

    // K1: convert_wt U hist
    convert_hist<<<128 + NUM_EDGES / 256, 256, 0, stream>>>(W, Wt, dst, counts);

    // scan
    scan1_kernel<<<(NUM_NODES + 1023) / 1024, 256, 0, stream>>>(counts, offsets, block_sums);
    scan2_kernel<<<1, 128, 0, stream>>>(block_sums, (NUM_NODES + 1023) / 1024);

    // K3: gemm U range-localized fill
    gemm_fill<<<GEMM_BLOCKS + NR * NCHUNK, 256, 0, stream>>>(
        feat, Wt, hself16, NUM_NODES, src, dst, offsets, block_sums, pos, perm_src);

    // K4: gather + finalize
    gather_finalize<<<NUM_NODES / 4, 256, 0, stream>>>(offsets, block_sums, perm_src, hself16, out);
}

// Round 5
// 304.312 us; speedup vs baseline: 3.3149x; 1.2834x over previous
//
#include <hip/hip_runtime.h>
#include <hip/hip_bf16.h>

// SAGEMeanConv: out = relu((segment_sum(h_self[src], dst) + h_self) / (deg+1))
// h_self = feat @ W via bf16 MFMA. Round 5: two-level LDS-binned edge sort.
//  Pass A: per-chunk LDS histogram over 782 buckets (128 nodes each), scan,
//          chunk-scatter of packed (ldst<<17|src) in contiguous ~64B runs
//          (single-XCD per run -> L2 write coalescing, no line thrash).
//  Pass B: one block per bucket: LDS counting sort by local node, then fused
//          gather + finalize (no global perm/offsets arrays at all).

#define IN_FEATS 256
#define OUT_FEATS 128
#define NUM_NODES 100000
#define NUM_EDGES 1600000

#define NB 782            // buckets of 128 nodes (ceil(100000/128))
#define EC 128            // edge chunks
#define CHUNK_E 12500     // edges per chunk; EC*CHUNK_E == NUM_EDGES
#define BCAP 3072         // max edges/bucket (uniform random: mean 2046, sigma~45)
#define GEMM_BLOCKS 782   // ceil(100000/128)

typedef __attribute__((ext_vector_type(8))) short short8;
typedef __attribute__((ext_vector_type(8))) unsigned short ushort8;
typedef __attribute__((ext_vector_type(4))) float f32x4;

#define LDA 72   // padded bf16 row stride in LDS

static __device__ inline unsigned short f2bfu(float x) {
    union { __hip_bfloat16 h; unsigned short u; } c;
    c.h = __float2bfloat16(x);
    return c.u;
}
static __device__ inline ushort2 f2bfu2(float x, float y) {
    union { __hip_bfloat162 h; ushort2 u; } c;
    c.h = __float22bfloat162_rn(make_float2(x, y));
    return c.u;
}
static __device__ inline float bf2f(unsigned short h) {
    return __uint_as_float((unsigned)h << 16);
}

// ---------------- K1: convert_wt (blocks 0..127) U passA hist (blocks 128..255) ----------------
__global__ __launch_bounds__(256) void convert_hist(
    const float* __restrict__ W, unsigned short* __restrict__ Wt,
    const int* __restrict__ dst, int* __restrict__ counts)
{
    int b = blockIdx.x;
    int t = threadIdx.x;
    if (b < 128) {
        int i = b * 256 + t;             // 32768 = 128n x 256k
        int n = i >> 8;
        int k = i & 255;
        Wt[i] = f2bfu(W[(size_t)k * OUT_FEATS + n]);
        return;
    }
    int c = b - 128;                     // chunk 0..127
    __shared__ int hist[NB];
    for (int i = t; i < NB; i += 256) hist[i] = 0;
    __syncthreads();
    const int4* dp = (const int4*)(dst + c * CHUNK_E);   // 3125 int4
    for (int i = t; i < CHUNK_E / 4; i += 256) {
        int4 d4 = dp[i];
        atomicAdd(&hist[d4.x >> 7], 1);
        atomicAdd(&hist[d4.y >> 7], 1);
        atomicAdd(&hist[d4.z >> 7], 1);
        atomicAdd(&hist[d4.w >> 7], 1);
    }
    __syncthreads();
    for (int i = t; i < NB; i += 256) counts[c * NB + i] = hist[i];
}

// ---------------- K2: per-bucket exclusive scan over chunks (in place) ----------------
__global__ __launch_bounds__(128) void scan_chunks(
    int* __restrict__ counts, int* __restrict__ bucket_total)
{
    __shared__ int sd[128];
    int b = blockIdx.x, t = threadIdx.x;
    int v = counts[t * NB + b];
    sd[t] = v;
    __syncthreads();
    for (int o = 1; o < 128; o <<= 1) {
        int x = (t >= o) ? sd[t - o] : 0;
        __syncthreads();
        sd[t] += x;
        __syncthreads();
    }
    counts[t * NB + b] = sd[t] - v;      // exclusive over chunks
    if (t == 127) bucket_total[b] = sd[127];
}

// ---------------- K3: exclusive scan of 782 bucket totals ----------------
__global__ __launch_bounds__(256) void scan_buckets(
    const int* __restrict__ bucket_total, int* __restrict__ bucket_base)
{
    __shared__ int sd[256];
    int t = threadIdx.x;
    int base = t * 4;
    int v0 = 0, v1 = 0, v2 = 0, v3 = 0;
    if (base + 3 < NB) {
        int4 v = *(const int4*)&bucket_total[base];
        v0 = v.x; v1 = v.y; v2 = v.z; v3 = v.w;
    } else {
        if (base + 0 < NB) v0 = bucket_total[base + 0];
        if (base + 1 < NB) v1 = bucket_total[base + 1];
        if (base + 2 < NB) v2 = bucket_total[base + 2];
        if (base + 3 < NB) v3 = bucket_total[base + 3];
    }
    int s = v0 + v1 + v2 + v3;
    sd[t] = s;
    __syncthreads();
    for (int o = 1; o < 256; o <<= 1) {
        int x = (t >= o) ? sd[t - o] : 0;
        __syncthreads();
        sd[t] += x;
        __syncthreads();
    }
    int e0 = sd[t] - s, e1 = e0 + v0, e2 = e1 + v1, e3 = e2 + v2;
    if (base + 0 < NB) bucket_base[base + 0] = e0;
    if (base + 1 < NB) bucket_base[base + 1] = e1;
    if (base + 2 < NB) bucket_base[base + 2] = e2;
    if (base + 3 < NB) bucket_base[base + 3] = e3;
}

// ---------------- K4: gemm (blocks 0..781) U passA scatter (blocks 782..909) ----------------
__global__ __launch_bounds__(256) void gemm_scatter(
    const float* __restrict__ feat, const unsigned short* __restrict__ Wt,
    unsigned short* __restrict__ hself16, int M,
    const int* __restrict__ src, const int* __restrict__ dst,
    const int* __restrict__ counts, const int* __restrict__ bucket_base,
    int* __restrict__ bedges)
{
    __shared__ char smem_raw[2 * 128 * LDA * 2];   // 36,864 B

    const int tid = threadIdx.x;

    if (blockIdx.x >= GEMM_BLOCKS) {
        // ---------------- scatter path ----------------
        int c = blockIdx.x - GEMM_BLOCKS;          // chunk 0..127
        int* cur = (int*)smem_raw;                 // NB cursors
        for (int i = tid; i < NB; i += 256)
            cur[i] = bucket_base[i] + counts[c * NB + i];
        __syncthreads();
        const int4* dp = (const int4*)(dst + c * CHUNK_E);
        const int4* sp = (const int4*)(src + c * CHUNK_E);
        for (int i = tid; i < CHUNK_E / 4; i += 256) {
            int4 d4 = dp[i];
            int4 s4 = sp[i];
            int dv[4] = { d4.x, d4.y, d4.z, d4.w };
            int sv[4] = { s4.x, s4.y, s4.z, s4.w };
#pragma unroll
            for (int j = 0; j < 4; ++j) {
                int d = dv[j];
                int slot = atomicAdd(&cur[d >> 7], 1);
                bedges[slot] = sv[j] | ((d & 127) << 17);
            }
        }
        return;
    }

    // ---------------- gemm path ----------------
    short* smem  = (short*)smem_raw;
    short* a_lds = smem;                      // A: [128 m][LDA k]
    short* b_lds = smem + 128 * LDA;          // B: [128 n][LDA k]

    const int w  = tid >> 6;
    const int l  = tid & 63;
    const int lf = l & 15;
    const int lg = l >> 4;
    const int wm = (w & 1) * 64;
    const int wn = (w >> 1) * 64;
    const int bm0 = blockIdx.x * 128;

    f32x4 acc[4][4];
#pragma unroll
    for (int mt = 0; mt < 4; ++mt)
#pragma unroll
        for (int nt = 0; nt < 4; ++nt)
            acc[mt][nt] = (f32x4){0.f, 0.f, 0.f, 0.f};

    const int srow  = tid >> 1;               // 0..127
    const int skseg = (tid & 1) * 32;         // 0 or 32

    for (int k0 = 0; k0 < IN_FEATS; k0 += 64) {
        int grow = bm0 + srow;
        ushort8* ap = (ushort8*)(a_lds + srow * LDA + skseg);
        if (grow < M) {
            const float4* gp = (const float4*)(feat + (size_t)grow * IN_FEATS + k0 + skseg);
#pragma unroll
            for (int i = 0; i < 4; ++i) {
                float4 v0 = gp[2 * i];
                float4 v1 = gp[2 * i + 1];
                ushort2 c0 = f2bfu2(v0.x, v0.y);
                ushort2 c1 = f2bfu2(v0.z, v0.w);
                ushort2 c2 = f2bfu2(v1.x, v1.y);
                ushort2 c3 = f2bfu2(v1.z, v1.w);
                ushort8 p = { c0.x, c0.y, c1.x, c1.y, c2.x, c2.y, c3.x, c3.y };
                ap[i] = p;
            }
        } else {
            ushort8 z = { 0, 0, 0, 0, 0, 0, 0, 0 };
#pragma unroll
            for (int i = 0; i < 4; ++i) ap[i] = z;
        }
        {
            const ushort8* wp = (const ushort8*)(Wt + (size_t)srow * IN_FEATS + k0 + skseg);
            ushort8* bp = (ushort8*)(b_lds + srow * LDA + skseg);
#pragma unroll
            for (int i = 0; i < 4; ++i) bp[i] = wp[i];
        }
        __syncthreads();

#pragma unroll
        for (int ks = 0; ks < 64; ks += 32) {
            short8 af[4], bfr[4];
#pragma unroll
            for (int mt = 0; mt < 4; ++mt)
                af[mt] = *(const short8*)(a_lds + (wm + mt * 16 + lf) * LDA + ks + lg * 8);
#pragma unroll
            for (int nt = 0; nt < 4; ++nt)
                bfr[nt] = *(const short8*)(b_lds + (wn + nt * 16 + lf) * LDA + ks + lg * 8);
#pragma unroll
            for (int mt = 0; mt < 4; ++mt)
#pragma unroll
                for (int nt = 0; nt < 4; ++nt)
                    acc[mt][nt] = __builtin_amdgcn_mfma_f32_16x16x32_bf16(
                        af[mt], bfr[nt], acc[mt][nt], 0, 0, 0);
        }
        __syncthreads();
    }

    // epilogue: LDS transpose -> coalesced bf16 stores (wave-private 9216B regions)
    short* ep = smem + w * (64 * LDA);
#pragma unroll
    for (int mt = 0; mt < 4; ++mt)
#pragma unroll
        for (int nt = 0; nt < 4; ++nt)
#pragma unroll
            for (int r = 0; r < 4; r += 2) {
                ushort2 cv = f2bfu2(acc[mt][nt][r], acc[mt][nt][r + 1]);
                ep[(mt * 16 + lg * 4 + r) * LDA + nt * 16 + lf]     = (short)cv.x;
                ep[(mt * 16 + lg * 4 + r + 1) * LDA + nt * 16 + lf] = (short)cv.y;
            }
#pragma unroll
    for (int rr = 0; rr < 8; ++rr) {
        int row = rr * 8 + (l >> 3);
        short8 v = *(const short8*)(ep + row * LDA + (l & 7) * 8);
        int grow = bm0 + wm + row;
        if (grow < M)
            *(short8*)(hself16 + (size_t)grow * OUT_FEATS + wn + (l & 7) * 8) = v;
    }
}

// ---------------- K5: per-bucket LDS counting sort + fused gather/finalize ----------------
__global__ __launch_bounds__(256) void sort_gather(
    const int* __restrict__ bucket_base, const int* __restrict__ bucket_total,
    const int* __restrict__ bedges, const unsigned short* __restrict__ hself16,
    float* __restrict__ out)
{
    __shared__ int edata[BCAP];
    __shared__ int sorted[BCAP];
    __shared__ int cnt[128], off[128], cursor[128], sd[128];

    int b = blockIdx.x, t = threadIdx.x;
    int base = bucket_base[b];
    int tot = bucket_total[b];
    if (tot > BCAP) tot = BCAP;          // safety clamp (never hits: 22-sigma)
    int nnodes = NUM_NODES - b * 128;
    if (nnodes > 128) nnodes = 128;

    if (t < 128) cnt[t] = 0;
    __syncthreads();
    for (int i = t; i < tot; i += 256) {
        int e = bedges[base + i];
        edata[i] = e;
        atomicAdd(&cnt[e >> 17], 1);
    }
    __syncthreads();
    // exclusive scan of cnt[0..127] (all 256 threads hit the syncs)
    if (t < 128) sd[t] = cnt[t];
    __syncthreads();
    for (int o = 1; o < 128; o <<= 1) {
        int x = 0;
        if (t < 128 && t >= o) x = sd[t - o];
        __syncthreads();
        if (t < 128) sd[t] += x;
        __syncthreads();
    }
    if (t < 128) { int e = sd[t] - cnt[t]; off[t] = e; cursor[t] = e; }
    __syncthreads();
    for (int i = t; i < tot; i += 256) {
        int e = edata[i];
        int r = atomicAdd(&cursor[e >> 17], 1);
        sorted[r] = e & 0x1FFFF;
    }
    __syncthreads();

    // gather: 4 waves; wave w handles local nodes w, w+4, ...
    int w = t >> 6, l = t & 63, lg = l >> 4, lf = l & 15;
    for (int ln = w; ln < nnodes; ln += 4) {
        int beg = off[ln];
        int end = beg + cnt[ln];
        float acc[8];
#pragma unroll
        for (int i = 0; i < 8; ++i) acc[i] = 0.f;
        for (int j0 = beg; j0 < end; j0 += 8) {
            int ja = j0 + lg;
            int jb = j0 + 4 + lg;
            bool pa = ja < end;
            bool pb = jb < end;
            int sa = pa ? sorted[ja] : 0;
            int sb = pb ? sorted[jb] : 0;
            ushort8 ha = *(const ushort8*)(hself16 + (size_t)sa * OUT_FEATS + lf * 8);
            ushort8 hb = *(const ushort8*)(hself16 + (size_t)sb * OUT_FEATS + lf * 8);
            if (pa) {
#pragma unroll
                for (int i = 0; i < 8; ++i) acc[i] += bf2f(ha[i]);
            }
            if (pb) {
#pragma unroll
                for (int i = 0; i < 8; ++i) acc[i] += bf2f(hb[i]);
            }
        }
#pragma unroll
        for (int i = 0; i < 8; ++i) {
            acc[i] += __shfl_xor(acc[i], 16, 64);
            acc[i] += __shfl_xor(acc[i], 32, 64);
        }
        if (lg == 0) {
            int n = b * 128 + ln;
            float inv = 1.0f / (float)(end - beg + 1);
            ushort8 hs = *(const ushort8*)(hself16 + (size_t)n * OUT_FEATS + lf * 8);
            float v[8];
#pragma unroll
            for (int i = 0; i < 8; ++i)
                v[i] = fmaxf((acc[i] + bf2f(hs[i])) * inv, 0.f);
            float4* op = (float4*)(out + (size_t)n * OUT_FEATS + lf * 8);
            op[0] = make_float4(v[0], v[1], v[2], v[3]);
            op[1] = make_float4(v[4], v[5], v[6], v[7]);
        }
    }
}

extern "C" void kernel_launch(void* const* d_in, const int* in_sizes, int n_in,
                              void* d_out, int out_size, void* d_ws, size_t ws_size,
                              hipStream_t stream) {
    const float* feat = (const float*)d_in[0];
    const float* W    = (const float*)d_in[1];
    const int*   src  = (const int*)d_in[2];
    const int*   dst  = (const int*)d_in[3];
    float* out = (float*)d_out;

    char* ws = (char*)d_ws;
    unsigned short* hself16 = (unsigned short*)ws;                 // 25,600,000 B
    unsigned short* Wt      = (unsigned short*)(ws + 25600000);    //     65,536 B
    int* counts       = (int*)(ws + 25665536);                     //    400,384 B (EC*NB)
    int* bucket_total = (int*)(ws + 26065920);                     //      3,200 B
    int* bucket_base  = (int*)(ws + 26069120);                     //      3,200 B
    int* bedges       = (int*)(ws + 26072320);                     //  6,400,000 B
    // total 32,472,320 B

    // K1: convert_wt U passA histogram (no global atomics, no memset needed)
    convert_hist<<<256, 256, 0, stream>>>(W, Wt, dst, counts);

    // K2/K3: scans
    scan_chunks<<<NB, 128, 0, stream>>>(counts, bucket_total);
    scan_buckets<<<1, 256, 0, stream>>>(bucket_total, bucket_base);

    // K4: gemm U chunk-scatter (contiguous ~64B runs per (chunk,bucket))
    gemm_scatter<<<GEMM_BLOCKS + EC, 256, 0, stream>>>(
        feat, Wt, hself16, NUM_NODES, src, dst, counts, bucket_base, bedges);

    // K5: per-bucket LDS sort + fused gather + finalize
    sort_gather<<<NB, 256, 0, stream>>>(bucket_base, bucket_total, bedges, hself16, out);
}

// Round 6
// 289.390 us; speedup vs baseline: 3.4858x; 1.0516x over previous
//
#include <hip/hip_runtime.h>
#include <hip/hip_bf16.h>

// SAGEMeanConv: out = relu((segment_sum(h_self[src], dst) + h_self) / (deg+1))
// h_self = feat @ W via bf16 MFMA. Round 6:
//  - GEMM restructured: all of B (64KB, XOR-swizzled) resident in LDS, staged
//    once; A fragments loaded global->reg with inline fp32->bf16 cvt; NO
//    barriers in the K-loop (waves independent). 512-thr blocks, 256 rows each.
//  - gather: 16 edges in flight per wave (was 8).
//  - two-level LDS-binned edge sort unchanged (R5 structure).

#define IN_FEATS 256
#define OUT_FEATS 128
#define NUM_NODES 100000
#define NUM_EDGES 1600000

#define NB 782            // buckets of 128 nodes
#define EC 128            // edge chunks
#define CHUNK_E 12500     // edges per chunk
#define BCAP 3072         // max edges/bucket
#define GEMM_BLOCKS 391   // ceil(100000/256), 256 rows per block

typedef __attribute__((ext_vector_type(8))) short short8;
typedef __attribute__((ext_vector_type(8))) unsigned short ushort8;
typedef __attribute__((ext_vector_type(4))) float f32x4;

static __device__ inline unsigned short f2bfu(float x) {
    union { __hip_bfloat16 h; unsigned short u; } c;
    c.h = __float2bfloat16(x);
    return c.u;
}
static __device__ inline ushort2 f2bfu2(float x, float y) {
    union { __hip_bfloat162 h; ushort2 u; } c;
    c.h = __float22bfloat162_rn(make_float2(x, y));
    return c.u;
}
static __device__ inline float bf2f(unsigned short h) {
    return __uint_as_float((unsigned)h << 16);
}

// ---------------- K1: convert_wt (blocks 0..127) U passA hist (blocks 128..255) ----------------
__global__ __launch_bounds__(256) void convert_hist(
    const float* __restrict__ W, unsigned short* __restrict__ Wt,
    const int* __restrict__ dst, int* __restrict__ counts)
{
    int b = blockIdx.x;
    int t = threadIdx.x;
    if (b < 128) {
        int i = b * 256 + t;             // 32768 = 128n x 256k
        int n = i >> 8;
        int k = i & 255;
        Wt[i] = f2bfu(W[(size_t)k * OUT_FEATS + n]);
        return;
    }
    int c = b - 128;                     // chunk 0..127
    __shared__ int hist[NB];
    for (int i = t; i < NB; i += 256) hist[i] = 0;
    __syncthreads();
    const int4* dp = (const int4*)(dst + c * CHUNK_E);
    for (int i = t; i < CHUNK_E / 4; i += 256) {
        int4 d4 = dp[i];
        atomicAdd(&hist[d4.x >> 7], 1);
        atomicAdd(&hist[d4.y >> 7], 1);
        atomicAdd(&hist[d4.z >> 7], 1);
        atomicAdd(&hist[d4.w >> 7], 1);
    }
    __syncthreads();
    for (int i = t; i < NB; i += 256) counts[c * NB + i] = hist[i];
}

// ---------------- K2: per-bucket exclusive scan over chunks (in place) ----------------
__global__ __launch_bounds__(128) void scan_chunks(
    int* __restrict__ counts, int* __restrict__ bucket_total)
{
    __shared__ int sd[128];
    int b = blockIdx.x, t = threadIdx.x;
    int v = counts[t * NB + b];
    sd[t] = v;
    __syncthreads();
    for (int o = 1; o < 128; o <<= 1) {
        int x = (t >= o) ? sd[t - o] : 0;
        __syncthreads();
        sd[t] += x;
        __syncthreads();
    }
    counts[t * NB + b] = sd[t] - v;
    if (t == 127) bucket_total[b] = sd[127];
}

// ---------------- K3: exclusive scan of 782 bucket totals ----------------
__global__ __launch_bounds__(256) void scan_buckets(
    const int* __restrict__ bucket_total, int* __restrict__ bucket_base)
{
    __shared__ int sd[256];
    int t = threadIdx.x;
    int base = t * 4;
    int v0 = 0, v1 = 0, v2 = 0, v3 = 0;
    if (base + 3 < NB) {
        int4 v = *(const int4*)&bucket_total[base];
        v0 = v.x; v1 = v.y; v2 = v.z; v3 = v.w;
    } else {
        if (base + 0 < NB) v0 = bucket_total[base + 0];
        if (base + 1 < NB) v1 = bucket_total[base + 1];
        if (base + 2 < NB) v2 = bucket_total[base + 2];
        if (base + 3 < NB) v3 = bucket_total[base + 3];
    }
    int s = v0 + v1 + v2 + v3;
    sd[t] = s;
    __syncthreads();
    for (int o = 1; o < 256; o <<= 1) {
        int x = (t >= o) ? sd[t - o] : 0;
        __syncthreads();
        sd[t] += x;
        __syncthreads();
    }
    int e0 = sd[t] - s, e1 = e0 + v0, e2 = e1 + v1, e3 = e2 + v2;
    if (base + 0 < NB) bucket_base[base + 0] = e0;
    if (base + 1 < NB) bucket_base[base + 1] = e1;
    if (base + 2 < NB) bucket_base[base + 2] = e2;
    if (base + 3 < NB) bucket_base[base + 3] = e3;
}

// ---------------- K4: gemm (blocks 0..390) U chunk-scatter (391..518), 512 thr ----------------
__global__ __launch_bounds__(512, 4) void gemm_scatter(
    const float* __restrict__ feat, const unsigned short* __restrict__ Wt,
    unsigned short* __restrict__ hself16, int M,
    const int* __restrict__ src, const int* __restrict__ dst,
    const int* __restrict__ counts, const int* __restrict__ bucket_base,
    int* __restrict__ bedges)
{
    __shared__ char smem_raw[65536];
    const int tid = threadIdx.x;

    if (blockIdx.x >= GEMM_BLOCKS) {
        // ---------------- scatter path ----------------
        int c = blockIdx.x - GEMM_BLOCKS;          // chunk 0..127
        int* cur = (int*)smem_raw;
        for (int i = tid; i < NB; i += 512)
            cur[i] = bucket_base[i] + counts[c * NB + i];
        __syncthreads();
        const int4* dp = (const int4*)(dst + c * CHUNK_E);
        const int4* sp = (const int4*)(src + c * CHUNK_E);
        for (int i = tid; i < CHUNK_E / 4; i += 512) {
            int4 d4 = dp[i];
            int4 s4 = sp[i];
            int dv[4] = { d4.x, d4.y, d4.z, d4.w };
            int sv[4] = { s4.x, s4.y, s4.z, s4.w };
#pragma unroll
            for (int j = 0; j < 4; ++j) {
                int d = dv[j];
                int slot = atomicAdd(&cur[d >> 7], 1);
                bedges[slot] = sv[j] | ((d & 127) << 17);
            }
        }
        return;
    }

    // ---------------- gemm path ----------------
    unsigned short* Bl = (unsigned short*)smem_raw;   // B: [n=128][k-granule swizzled]

    // stage ALL of B once: 4096 granules of 16B, XOR-swizzled (g ^ (n&7))
    {
        int n = tid >> 2;                    // 0..127
        int gbase = (tid & 3) * 8;           // 0,8,16,24
#pragma unroll
        for (int j = 0; j < 8; ++j) {
            int g = gbase + j;
            ushort8 v = *(const ushort8*)(Wt + (size_t)n * IN_FEATS + g * 8);
            *(ushort8*)(Bl + n * IN_FEATS + ((g ^ (n & 7)) * 8)) = v;
        }
    }
    __syncthreads();

    const int w  = tid >> 6;                 // wave 0..7, owns rows w*32..+31
    const int l  = tid & 63;
    const int lf = l & 15;
    const int lg = (l >> 4) & 3;
    const int bm0 = blockIdx.x * 256;
    const int rbase = bm0 + w * 32;

    f32x4 acc[2][8];
#pragma unroll
    for (int mt = 0; mt < 2; ++mt)
#pragma unroll
        for (int nt = 0; nt < 8; ++nt)
            acc[mt][nt] = (f32x4){0.f, 0.f, 0.f, 0.f};

#pragma unroll 2
    for (int k0 = 0; k0 < IN_FEATS; k0 += 32) {
        int k8 = k0 >> 3;
        // A fragments: global -> reg, inline cvt
        short8 af[2];
#pragma unroll
        for (int mt = 0; mt < 2; ++mt) {
            int grow = rbase + mt * 16 + lf;
            if (grow < M) {
                const float4* ap = (const float4*)(feat + (size_t)grow * IN_FEATS + k0 + lg * 8);
                float4 f0 = ap[0];
                float4 f1 = ap[1];
                ushort2 c0 = f2bfu2(f0.x, f0.y);
                ushort2 c1 = f2bfu2(f0.z, f0.w);
                ushort2 c2 = f2bfu2(f1.x, f1.y);
                ushort2 c3 = f2bfu2(f1.z, f1.w);
                af[mt] = (short8){ (short)c0.x, (short)c0.y, (short)c1.x, (short)c1.y,
                                   (short)c2.x, (short)c2.y, (short)c3.x, (short)c3.y };
            } else {
                af[mt] = (short8){ 0, 0, 0, 0, 0, 0, 0, 0 };
            }
        }
        // B fragments from LDS (swizzled), 2 n-halves to bound registers
#pragma unroll
        for (int nh = 0; nh < 2; ++nh) {
            short8 bf[4];
#pragma unroll
            for (int q = 0; q < 4; ++q) {
                int nt = nh * 4 + q;
                int n = nt * 16 + lf;
                int g = (k8 + lg) ^ (lf & 7);
                bf[q] = *(const short8*)(Bl + n * IN_FEATS + g * 8);
            }
#pragma unroll
            for (int q = 0; q < 4; ++q) {
                int nt = nh * 4 + q;
                acc[0][nt] = __builtin_amdgcn_mfma_f32_16x16x32_bf16(af[0], bf[q], acc[0][nt], 0, 0, 0);
                acc[1][nt] = __builtin_amdgcn_mfma_f32_16x16x32_bf16(af[1], bf[q], acc[1][nt], 0, 0, 0);
            }
        }
    }

    // ---- epilogue: reuse LDS (B dead) for row-major transpose, coalesced stores ----
    __syncthreads();                          // all waves done reading B
    unsigned short* ep = (unsigned short*)smem_raw;   // [256 rows][128 cols]
#pragma unroll
    for (int mt = 0; mt < 2; ++mt)
#pragma unroll
        for (int nt = 0; nt < 8; ++nt)
#pragma unroll
            for (int r = 0; r < 4; ++r) {
                int row = w * 32 + mt * 16 + lg * 4 + r;
                ep[row * 128 + nt * 16 + lf] = f2bfu(acc[mt][nt][r]);
            }
    __syncthreads();
#pragma unroll
    for (int i = 0; i < 8; ++i) {
        int lrow = w * 32 + i * 4 + (l >> 4);
        ushort8 v = *(const ushort8*)(ep + lrow * 128 + (l & 15) * 8);
        int grow = bm0 + lrow;
        if (grow < M)
            *(ushort8*)(hself16 + (size_t)grow * OUT_FEATS + (l & 15) * 8) = v;
    }
}

// ---------------- K5: per-bucket LDS counting sort + fused gather/finalize ----------------
__global__ __launch_bounds__(256) void sort_gather(
    const int* __restrict__ bucket_base, const int* __restrict__ bucket_total,
    const int* __restrict__ bedges, const unsigned short* __restrict__ hself16,
    float* __restrict__ out)
{
    __shared__ int edata[BCAP];
    __shared__ int sorted[BCAP];
    __shared__ int cnt[128], off[128], cursor[128], sd[128];

    int b = blockIdx.x, t = threadIdx.x;
    int base = bucket_base[b];
    int tot = bucket_total[b];
    if (tot > BCAP) tot = BCAP;
    int nnodes = NUM_NODES - b * 128;
    if (nnodes > 128) nnodes = 128;

    if (t < 128) cnt[t] = 0;
    __syncthreads();
    for (int i = t; i < tot; i += 256) {
        int e = bedges[base + i];
        edata[i] = e;
        atomicAdd(&cnt[e >> 17], 1);
    }
    __syncthreads();
    if (t < 128) sd[t] = cnt[t];
    __syncthreads();
    for (int o = 1; o < 128; o <<= 1) {
        int x = 0;
        if (t < 128 && t >= o) x = sd[t - o];
        __syncthreads();
        if (t < 128) sd[t] += x;
        __syncthreads();
    }
    if (t < 128) { int e = sd[t] - cnt[t]; off[t] = e; cursor[t] = e; }
    __syncthreads();
    for (int i = t; i < tot; i += 256) {
        int e = edata[i];
        int r = atomicAdd(&cursor[e >> 17], 1);
        sorted[r] = e & 0x1FFFF;
    }
    __syncthreads();

    // gather: 4 waves; wave w handles local nodes w, w+4, ...; 16 edges in flight
    int w = t >> 6, l = t & 63, lg = l >> 4, lf = l & 15;
    for (int ln = w; ln < nnodes; ln += 4) {
        int beg = off[ln];
        int end = beg + cnt[ln];
        float acc[8];
#pragma unroll
        for (int i = 0; i < 8; ++i) acc[i] = 0.f;
        for (int j0 = beg; j0 < end; j0 += 16) {
            int  jj[4];
            bool pp[4];
            int  ss[4];
#pragma unroll
            for (int q = 0; q < 4; ++q) {
                jj[q] = j0 + q * 4 + lg;
                pp[q] = jj[q] < end;
                ss[q] = pp[q] ? sorted[jj[q]] : 0;
            }
            ushort8 h[4];
#pragma unroll
            for (int q = 0; q < 4; ++q)
                h[q] = *(const ushort8*)(hself16 + (size_t)ss[q] * OUT_FEATS + lf * 8);
#pragma unroll
            for (int q = 0; q < 4; ++q)
                if (pp[q]) {
#pragma unroll
                    for (int i = 0; i < 8; ++i) acc[i] += bf2f(h[q][i]);
                }
        }
#pragma unroll
        for (int i = 0; i < 8; ++i) {
            acc[i] += __shfl_xor(acc[i], 16, 64);
            acc[i] += __shfl_xor(acc[i], 32, 64);
        }
        if (lg == 0) {
            int n = b * 128 + ln;
            float inv = 1.0f / (float)(end - beg + 1);
            ushort8 hs = *(const ushort8*)(hself16 + (size_t)n * OUT_FEATS + lf * 8);
            float v[8];
#pragma unroll
            for (int i = 0; i < 8; ++i)
                v[i] = fmaxf((acc[i] + bf2f(hs[i])) * inv, 0.f);
            float4* op = (float4*)(out + (size_t)n * OUT_FEATS + lf * 8);
            op[0] = make_float4(v[0], v[1], v[2], v[3]);
            op[1] = make_float4(v[4], v[5], v[6], v[7]);
        }
    }
}

extern "C" void kernel_launch(void* const* d_in, const int* in_sizes, int n_in,
                              void* d_out, int out_size, void* d_ws, size_t ws_size,
                              hipStream_t stream) {
    const float* feat = (const float*)d_in[0];
    const float* W    = (const float*)d_in[1];
    const int*   src  = (const int*)d_in[2];
    const int*   dst  = (const int*)d_in[3];
    float* out = (float*)d_out;

    char* ws = (char*)d_ws;
    unsigned short* hself16 = (unsigned short*)ws;                 // 25,600,000 B
    unsigned short* Wt      = (unsigned short*)(ws + 25600000);    //     65,536 B
    int* counts       = (int*)(ws + 25665536);                     //    400,384 B
    int* bucket_total = (int*)(ws + 26065920);                     //      3,200 B
    int* bucket_base  = (int*)(ws + 26069120);                     //      3,200 B
    int* bedges       = (int*)(ws + 26072320);                     //  6,400,000 B

    convert_hist<<<256, 256, 0, stream>>>(W, Wt, dst, counts);
    scan_chunks<<<NB, 128, 0, stream>>>(counts, bucket_total);
    scan_buckets<<<1, 256, 0, stream>>>(bucket_total, bucket_base);
    gemm_scatter<<<GEMM_BLOCKS + EC, 512, 0, stream>>>(
        feat, Wt, hself16, NUM_NODES, src, dst, counts, bucket_base, bedges);
    sort_gather<<<NB, 256, 0, stream>>>(bucket_base, bucket_total, bedges, hself16, out);
}

// Round 7
// 287.104 us; speedup vs baseline: 3.5136x; 1.0080x over previous
//
#include <hip/hip_runtime.h>
#include <hip/hip_bf16.h>

// SAGEMeanConv: out = relu((segment_sum(h_self[src], dst) + h_self) / (deg+1))
// h_self = feat @ W via bf16 MFMA. Round 7:
//  - sort_gather: dropped edata[] LDS buffer (re-read bedges from global in
//    phase 2, L2-hot) -> LDS 26.6KB -> 14.3KB; __launch_bounds__(256,6) for
//    ~6 blocks/CU. Attacks the 28.7% occupancy / latency-bound top dispatch.
//  - GEMM (barrier-free, B fully LDS-resident) and two-level edge sort unchanged.

#define IN_FEATS 256
#define OUT_FEATS 128
#define NUM_NODES 100000
#define NUM_EDGES 1600000

#define NB 782            // buckets of 128 nodes
#define EC 128            // edge chunks
#define CHUNK_E 12500     // edges per chunk
#define BCAP 3072         // max edges/bucket
#define GEMM_BLOCKS 391   // ceil(100000/256), 256 rows per block

typedef __attribute__((ext_vector_type(8))) short short8;
typedef __attribute__((ext_vector_type(8))) unsigned short ushort8;
typedef __attribute__((ext_vector_type(4))) float f32x4;

static __device__ inline unsigned short f2bfu(float x) {
    union { __hip_bfloat16 h; unsigned short u; } c;
    c.h = __float2bfloat16(x);
    return c.u;
}
static __device__ inline ushort2 f2bfu2(float x, float y) {
    union { __hip_bfloat162 h; ushort2 u; } c;
    c.h = __float22bfloat162_rn(make_float2(x, y));
    return c.u;
}
static __device__ inline float bf2f(unsigned short h) {
    return __uint_as_float((unsigned)h << 16);
}

// ---------------- K1: convert_wt (blocks 0..127) U passA hist (blocks 128..255) ----------------
__global__ __launch_bounds__(256) void convert_hist(
    const float* __restrict__ W, unsigned short* __restrict__ Wt,
    const int* __restrict__ dst, int* __restrict__ counts)
{
    int b = blockIdx.x;
    int t = threadIdx.x;
    if (b < 128) {
        int i = b * 256 + t;             // 32768 = 128n x 256k
        int n = i >> 8;
        int k = i & 255;
        Wt[i] = f2bfu(W[(size_t)k * OUT_FEATS + n]);
        return;
    }
    int c = b - 128;                     // chunk 0..127
    __shared__ int hist[NB];
    for (int i = t; i < NB; i += 256) hist[i] = 0;
    __syncthreads();
    const int4* dp = (const int4*)(dst + c * CHUNK_E);
    for (int i = t; i < CHUNK_E / 4; i += 256) {
        int4 d4 = dp[i];
        atomicAdd(&hist[d4.x >> 7], 1);
        atomicAdd(&hist[d4.y >> 7], 1);
        atomicAdd(&hist[d4.z >> 7], 1);
        atomicAdd(&hist[d4.w >> 7], 1);
    }
    __syncthreads();
    for (int i = t; i < NB; i += 256) counts[c * NB + i] = hist[i];
}

// ---------------- K2: per-bucket exclusive scan over chunks (in place) ----------------
__global__ __launch_bounds__(128) void scan_chunks(
    int* __restrict__ counts, int* __restrict__ bucket_total)
{
    __shared__ int sd[128];
    int b = blockIdx.x, t = threadIdx.x;
    int v = counts[t * NB + b];
    sd[t] = v;
    __syncthreads();
    for (int o = 1; o < 128; o <<= 1) {
        int x = (t >= o) ? sd[t - o] : 0;
        __syncthreads();
        sd[t] += x;
        __syncthreads();
    }
    counts[t * NB + b] = sd[t] - v;
    if (t == 127) bucket_total[b] = sd[127];
}

// ---------------- K3: exclusive scan of 782 bucket totals ----------------
__global__ __launch_bounds__(256) void scan_buckets(
    const int* __restrict__ bucket_total, int* __restrict__ bucket_base)
{
    __shared__ int sd[256];
    int t = threadIdx.x;
    int base = t * 4;
    int v0 = 0, v1 = 0, v2 = 0, v3 = 0;
    if (base + 3 < NB) {
        int4 v = *(const int4*)&bucket_total[base];
        v0 = v.x; v1 = v.y; v2 = v.z; v3 = v.w;
    } else {
        if (base + 0 < NB) v0 = bucket_total[base + 0];
        if (base + 1 < NB) v1 = bucket_total[base + 1];
        if (base + 2 < NB) v2 = bucket_total[base + 2];
        if (base + 3 < NB) v3 = bucket_total[base + 3];
    }
    int s = v0 + v1 + v2 + v3;
    sd[t] = s;
    __syncthreads();
    for (int o = 1; o < 256; o <<= 1) {
        int x = (t >= o) ? sd[t - o] : 0;
        __syncthreads();
        sd[t] += x;
        __syncthreads();
    }
    int e0 = sd[t] - s, e1 = e0 + v0, e2 = e1 + v1, e3 = e2 + v2;
    if (base + 0 < NB) bucket_base[base + 0] = e0;
    if (base + 1 < NB) bucket_base[base + 1] = e1;
    if (base + 2 < NB) bucket_base[base + 2] = e2;
    if (base + 3 < NB) bucket_base[base + 3] = e3;
}

// ---------------- K4: gemm (blocks 0..390) U chunk-scatter (391..518), 512 thr ----------------
__global__ __launch_bounds__(512, 4) void gemm_scatter(
    const float* __restrict__ feat, const unsigned short* __restrict__ Wt,
    unsigned short* __restrict__ hself16, int M,
    const int* __restrict__ src, const int* __restrict__ dst,
    const int* __restrict__ counts, const int* __restrict__ bucket_base,
    int* __restrict__ bedges)
{
    __shared__ char smem_raw[65536];
    const int tid = threadIdx.x;

    if (blockIdx.x >= GEMM_BLOCKS) {
        // ---------------- scatter path ----------------
        int c = blockIdx.x - GEMM_BLOCKS;          // chunk 0..127
        int* cur = (int*)smem_raw;
        for (int i = tid; i < NB; i += 512)
            cur[i] = bucket_base[i] + counts[c * NB + i];
        __syncthreads();
        const int4* dp = (const int4*)(dst + c * CHUNK_E);
        const int4* sp = (const int4*)(src + c * CHUNK_E);
        for (int i = tid; i < CHUNK_E / 4; i += 512) {
            int4 d4 = dp[i];
            int4 s4 = sp[i];
            int dv[4] = { d4.x, d4.y, d4.z, d4.w };
            int sv[4] = { s4.x, s4.y, s4.z, s4.w };
#pragma unroll
            for (int j = 0; j < 4; ++j) {
                int d = dv[j];
                int slot = atomicAdd(&cur[d >> 7], 1);
                bedges[slot] = sv[j] | ((d & 127) << 17);
            }
        }
        return;
    }

    // ---------------- gemm path ----------------
    unsigned short* Bl = (unsigned short*)smem_raw;   // B: [n=128][k-granule swizzled]

    // stage ALL of B once: 4096 granules of 16B, XOR-swizzled (g ^ (n&7))
    {
        int n = tid >> 2;                    // 0..127
        int gbase = (tid & 3) * 8;           // 0,8,16,24
#pragma unroll
        for (int j = 0; j < 8; ++j) {
            int g = gbase + j;
            ushort8 v = *(const ushort8*)(Wt + (size_t)n * IN_FEATS + g * 8);
            *(ushort8*)(Bl + n * IN_FEATS + ((g ^ (n & 7)) * 8)) = v;
        }
    }
    __syncthreads();

    const int w  = tid >> 6;                 // wave 0..7, owns rows w*32..+31
    const int l  = tid & 63;
    const int lf = l & 15;
    const int lg = (l >> 4) & 3;
    const int bm0 = blockIdx.x * 256;
    const int rbase = bm0 + w * 32;

    f32x4 acc[2][8];
#pragma unroll
    for (int mt = 0; mt < 2; ++mt)
#pragma unroll
        for (int nt = 0; nt < 8; ++nt)
            acc[mt][nt] = (f32x4){0.f, 0.f, 0.f, 0.f};

#pragma unroll 2
    for (int k0 = 0; k0 < IN_FEATS; k0 += 32) {
        int k8 = k0 >> 3;
        // A fragments: global -> reg, inline cvt
        short8 af[2];
#pragma unroll
        for (int mt = 0; mt < 2; ++mt) {
            int grow = rbase + mt * 16 + lf;
            if (grow < M) {
                const float4* ap = (const float4*)(feat + (size_t)grow * IN_FEATS + k0 + lg * 8);
                float4 f0 = ap[0];
                float4 f1 = ap[1];
                ushort2 c0 = f2bfu2(f0.x, f0.y);
                ushort2 c1 = f2bfu2(f0.z, f0.w);
                ushort2 c2 = f2bfu2(f1.x, f1.y);
                ushort2 c3 = f2bfu2(f1.z, f1.w);
                af[mt] = (short8){ (short)c0.x, (short)c0.y, (short)c1.x, (short)c1.y,
                                   (short)c2.x, (short)c2.y, (short)c3.x, (short)c3.y };
            } else {
                af[mt] = (short8){ 0, 0, 0, 0, 0, 0, 0, 0 };
            }
        }
        // B fragments from LDS (swizzled), 2 n-halves to bound registers
#pragma unroll
        for (int nh = 0; nh < 2; ++nh) {
            short8 bf[4];
#pragma unroll
            for (int q = 0; q < 4; ++q) {
                int nt = nh * 4 + q;
                int n = nt * 16 + lf;
                int g = (k8 + lg) ^ (lf & 7);
                bf[q] = *(const short8*)(Bl + n * IN_FEATS + g * 8);
            }
#pragma unroll
            for (int q = 0; q < 4; ++q) {
                int nt = nh * 4 + q;
                acc[0][nt] = __builtin_amdgcn_mfma_f32_16x16x32_bf16(af[0], bf[q], acc[0][nt], 0, 0, 0);
                acc[1][nt] = __builtin_amdgcn_mfma_f32_16x16x32_bf16(af[1], bf[q], acc[1][nt], 0, 0, 0);
            }
        }
    }

    // ---- epilogue: reuse LDS (B dead) for row-major transpose, coalesced stores ----
    __syncthreads();                          // all waves done reading B
    unsigned short* ep = (unsigned short*)smem_raw;   // [256 rows][128 cols]
#pragma unroll
    for (int mt = 0; mt < 2; ++mt)
#pragma unroll
        for (int nt = 0; nt < 8; ++nt)
#pragma unroll
            for (int r = 0; r < 4; ++r) {
                int row = w * 32 + mt * 16 + lg * 4 + r;
                ep[row * 128 + nt * 16 + lf] = f2bfu(acc[mt][nt][r]);
            }
    __syncthreads();
#pragma unroll
    for (int i = 0; i < 8; ++i) {
        int lrow = w * 32 + i * 4 + (l >> 4);
        ushort8 v = *(const ushort8*)(ep + lrow * 128 + (l & 15) * 8);
        int grow = bm0 + lrow;
        if (grow < M)
            *(ushort8*)(hself16 + (size_t)grow * OUT_FEATS + (l & 15) * 8) = v;
    }
}

// ---------------- K5: per-bucket LDS counting sort + fused gather/finalize ----------------
// LDS slimmed to 14.3KB (no edata; phase 2 re-reads bedges, L2-hot) -> 6 blocks/CU.
__global__ __launch_bounds__(256, 6) void sort_gather(
    const int* __restrict__ bucket_base, const int* __restrict__ bucket_total,
    const int* __restrict__ bedges, const unsigned short* __restrict__ hself16,
    float* __restrict__ out)
{
    __shared__ int sorted[BCAP];
    __shared__ int cnt[128], off[128], cursor[128], sd[128];

    int b = blockIdx.x, t = threadIdx.x;
    int base = bucket_base[b];
    int tot = bucket_total[b];
    if (tot > BCAP) tot = BCAP;
    int nnodes = NUM_NODES - b * 128;
    if (nnodes > 128) nnodes = 128;

    if (t < 128) cnt[t] = 0;
    __syncthreads();
    for (int i = t; i < tot; i += 256)
        atomicAdd(&cnt[bedges[base + i] >> 17], 1);
    __syncthreads();
    if (t < 128) sd[t] = cnt[t];
    __syncthreads();
    for (int o = 1; o < 128; o <<= 1) {
        int x = 0;
        if (t < 128 && t >= o) x = sd[t - o];
        __syncthreads();
        if (t < 128) sd[t] += x;
        __syncthreads();
    }
    if (t < 128) { int e = sd[t] - cnt[t]; off[t] = e; cursor[t] = e; }
    __syncthreads();
    for (int i = t; i < tot; i += 256) {
        int e = bedges[base + i];           // re-read (L2-hot)
        int r = atomicAdd(&cursor[e >> 17], 1);
        sorted[r] = e & 0x1FFFF;
    }
    __syncthreads();

    // gather: 4 waves; wave w handles local nodes w, w+4, ...; 16 edges in flight
    int w = t >> 6, l = t & 63, lg = l >> 4, lf = l & 15;
    for (int ln = w; ln < nnodes; ln += 4) {
        int beg = off[ln];
        int end = beg + cnt[ln];
        float acc[8];
#pragma unroll
        for (int i = 0; i < 8; ++i) acc[i] = 0.f;
        for (int j0 = beg; j0 < end; j0 += 16) {
            int  jj[4];
            bool pp[4];
            int  ss[4];
#pragma unroll
            for (int q = 0; q < 4; ++q) {
                jj[q] = j0 + q * 4 + lg;
                pp[q] = jj[q] < end;
                ss[q] = pp[q] ? sorted[jj[q]] : 0;
            }
            ushort8 h[4];
#pragma unroll
            for (int q = 0; q < 4; ++q)
                h[q] = *(const ushort8*)(hself16 + (size_t)ss[q] * OUT_FEATS + lf * 8);
#pragma unroll
            for (int q = 0; q < 4; ++q)
                if (pp[q]) {
#pragma unroll
                    for (int i = 0; i < 8; ++i) acc[i] += bf2f(h[q][i]);
                }
        }
#pragma unroll
        for (int i = 0; i < 8; ++i) {
            acc[i] += __shfl_xor(acc[i], 16, 64);
            acc[i] += __shfl_xor(acc[i], 32, 64);
        }
        if (lg == 0) {
            int n = b * 128 + ln;
            float inv = 1.0f / (float)(end - beg + 1);
            ushort8 hs = *(const ushort8*)(hself16 + (size_t)n * OUT_FEATS + lf * 8);
            float v[8];
#pragma unroll
            for (int i = 0; i < 8; ++i)
                v[i] = fmaxf((acc[i] + bf2f(hs[i])) * inv, 0.f);
            float4* op = (float4*)(out + (size_t)n * OUT_FEATS + lf * 8);
            op[0] = make_float4(v[0], v[1], v[2], v[3]);
            op[1] = make_float4(v[4], v[5], v[6], v[7]);
        }
    }
}

extern "C" void kernel_launch(void* const* d_in, const int* in_sizes, int n_in,
                              void* d_out, int out_size, void* d_ws, size_t ws_size,
                              hipStream_t stream) {
    const float* feat = (const float*)d_in[0];
    const float* W    = (const float*)d_in[1];
    const int*   src  = (const int*)d_in[2];
    const int*   dst  = (const int*)d_in[3];
    float* out = (float*)d_out;

    char* ws = (char*)d_ws;
    unsigned short* hself16 = (unsigned short*)ws;                 // 25,600,000 B
    unsigned short* Wt      = (unsigned short*)(ws + 25600000);    //     65,536 B
    int* counts       = (int*)(ws + 25665536);                     //    400,384 B
    int* bucket_total = (int*)(ws + 26065920);                     //      3,200 B
    int* bucket_base  = (int*)(ws + 26069120);                     //      3,200 B
    int* bedges       = (int*)(ws + 26072320);                     //  6,400,000 B

    convert_hist<<<256, 256, 0, stream>>>(W, Wt, dst, counts);
    scan_chunks<<<NB, 128, 0, stream>>>(counts, bucket_total);
    scan_buckets<<<1, 256, 0, stream>>>(bucket_total, bucket_base);
    gemm_scatter<<<GEMM_BLOCKS + EC, 512, 0, stream>>>(
        feat, Wt, hself16, NUM_NODES, src, dst, counts, bucket_base, bedges);
    sort_gather<<<NB, 256, 0, stream>>>(bucket_base, bucket_total, bedges, hself16, out);
}

// Round 8
// 285.337 us; speedup vs baseline: 3.5353x; 1.0062x over previous
//
#include <hip/hip_runtime.h>
#include <hip/hip_bf16.h>

// SAGEMeanConv: out = relu((segment_sum(h_self[src], dst) + h_self) / (deg+1))
// h_self = feat @ W via bf16 MFMA. Round 8:
//  - sort_gather widened to 512 threads / 8 waves per block (NB=782 blocks was
//    grid-capping occupancy at ~12 waves/CU; now ~24). Wave w handles local
//    nodes w, w+8, ... (16 nodes/wave). LDS unchanged at 14.3KB.
//  - GEMM (barrier-free, B fully LDS-resident) and two-level edge sort unchanged.

#define IN_FEATS 256
#define OUT_FEATS 128
#define NUM_NODES 100000
#define NUM_EDGES 1600000

#define NB 782            // buckets of 128 nodes
#define EC 128            // edge chunks
#define CHUNK_E 12500     // edges per chunk
#define BCAP 3072         // max edges/bucket
#define GEMM_BLOCKS 391   // ceil(100000/256), 256 rows per block

typedef __attribute__((ext_vector_type(8))) short short8;
typedef __attribute__((ext_vector_type(8))) unsigned short ushort8;
typedef __attribute__((ext_vector_type(4))) float f32x4;

static __device__ inline unsigned short f2bfu(float x) {
    union { __hip_bfloat16 h; unsigned short u; } c;
    c.h = __float2bfloat16(x);
    return c.u;
}
static __device__ inline ushort2 f2bfu2(float x, float y) {
    union { __hip_bfloat162 h; ushort2 u; } c;
    c.h = __float22bfloat162_rn(make_float2(x, y));
    return c.u;
}
static __device__ inline float bf2f(unsigned short h) {
    return __uint_as_float((unsigned)h << 16);
}

// ---------------- K1: convert_wt (blocks 0..127) U passA hist (blocks 128..255) ----------------
__global__ __launch_bounds__(256) void convert_hist(
    const float* __restrict__ W, unsigned short* __restrict__ Wt,
    const int* __restrict__ dst, int* __restrict__ counts)
{
    int b = blockIdx.x;
    int t = threadIdx.x;
    if (b < 128) {
        int i = b * 256 + t;             // 32768 = 128n x 256k
        int n = i >> 8;
        int k = i & 255;
        Wt[i] = f2bfu(W[(size_t)k * OUT_FEATS + n]);
        return;
    }
    int c = b - 128;                     // chunk 0..127
    __shared__ int hist[NB];
    for (int i = t; i < NB; i += 256) hist[i] = 0;
    __syncthreads();
    const int4* dp = (const int4*)(dst + c * CHUNK_E);
    for (int i = t; i < CHUNK_E / 4; i += 256) {
        int4 d4 = dp[i];
        atomicAdd(&hist[d4.x >> 7], 1);
        atomicAdd(&hist[d4.y >> 7], 1);
        atomicAdd(&hist[d4.z >> 7], 1);
        atomicAdd(&hist[d4.w >> 7], 1);
    }
    __syncthreads();
    for (int i = t; i < NB; i += 256) counts[c * NB + i] = hist[i];
}

// ---------------- K2: per-bucket exclusive scan over chunks (in place) ----------------
__global__ __launch_bounds__(128) void scan_chunks(
    int* __restrict__ counts, int* __restrict__ bucket_total)
{
    __shared__ int sd[128];
    int b = blockIdx.x, t = threadIdx.x;
    int v = counts[t * NB + b];
    sd[t] = v;
    __syncthreads();
    for (int o = 1; o < 128; o <<= 1) {
        int x = (t >= o) ? sd[t - o] : 0;
        __syncthreads();
        sd[t] += x;
        __syncthreads();
    }
    counts[t * NB + b] = sd[t] - v;
    if (t == 127) bucket_total[b] = sd[127];
}

// ---------------- K3: exclusive scan of 782 bucket totals ----------------
__global__ __launch_bounds__(256) void scan_buckets(
    const int* __restrict__ bucket_total, int* __restrict__ bucket_base)
{
    __shared__ int sd[256];
    int t = threadIdx.x;
    int base = t * 4;
    int v0 = 0, v1 = 0, v2 = 0, v3 = 0;
    if (base + 3 < NB) {
        int4 v = *(const int4*)&bucket_total[base];
        v0 = v.x; v1 = v.y; v2 = v.z; v3 = v.w;
    } else {
        if (base + 0 < NB) v0 = bucket_total[base + 0];
        if (base + 1 < NB) v1 = bucket_total[base + 1];
        if (base + 2 < NB) v2 = bucket_total[base + 2];
        if (base + 3 < NB) v3 = bucket_total[base + 3];
    }
    int s = v0 + v1 + v2 + v3;
    sd[t] = s;
    __syncthreads();
    for (int o = 1; o < 256; o <<= 1) {
        int x = (t >= o) ? sd[t - o] : 0;
        __syncthreads();
        sd[t] += x;
        __syncthreads();
    }
    int e0 = sd[t] - s, e1 = e0 + v0, e2 = e1 + v1, e3 = e2 + v2;
    if (base + 0 < NB) bucket_base[base + 0] = e0;
    if (base + 1 < NB) bucket_base[base + 1] = e1;
    if (base + 2 < NB) bucket_base[base + 2] = e2;
    if (base + 3 < NB) bucket_base[base + 3] = e3;
}

// ---------------- K4: gemm (blocks 0..390) U chunk-scatter (391..518), 512 thr ----------------
__global__ __launch_bounds__(512, 4) void gemm_scatter(
    const float* __restrict__ feat, const unsigned short* __restrict__ Wt,
    unsigned short* __restrict__ hself16, int M,
    const int* __restrict__ src, const int* __restrict__ dst,
    const int* __restrict__ counts, const int* __restrict__ bucket_base,
    int* __restrict__ bedges)
{
    __shared__ char smem_raw[65536];
    const int tid = threadIdx.x;

    if (blockIdx.x >= GEMM_BLOCKS) {
        // ---------------- scatter path ----------------
        int c = blockIdx.x - GEMM_BLOCKS;          // chunk 0..127
        int* cur = (int*)smem_raw;
        for (int i = tid; i < NB; i += 512)
            cur[i] = bucket_base[i] + counts[c * NB + i];
        __syncthreads();
        const int4* dp = (const int4*)(dst + c * CHUNK_E);
        const int4* sp = (const int4*)(src + c * CHUNK_E);
        for (int i = tid; i < CHUNK_E / 4; i += 512) {
            int4 d4 = dp[i];
            int4 s4 = sp[i];
            int dv[4] = { d4.x, d4.y, d4.z, d4.w };
            int sv[4] = { s4.x, s4.y, s4.z, s4.w };
#pragma unroll
            for (int j = 0; j < 4; ++j) {
                int d = dv[j];
                int slot = atomicAdd(&cur[d >> 7], 1);
                bedges[slot] = sv[j] | ((d & 127) << 17);
            }
        }
        return;
    }

    // ---------------- gemm path ----------------
    unsigned short* Bl = (unsigned short*)smem_raw;   // B: [n=128][k-granule swizzled]

    // stage ALL of B once: 4096 granules of 16B, XOR-swizzled (g ^ (n&7))
    {
        int n = tid >> 2;                    // 0..127
        int gbase = (tid & 3) * 8;           // 0,8,16,24
#pragma unroll
        for (int j = 0; j < 8; ++j) {
            int g = gbase + j;
            ushort8 v = *(const ushort8*)(Wt + (size_t)n * IN_FEATS + g * 8);
            *(ushort8*)(Bl + n * IN_FEATS + ((g ^ (n & 7)) * 8)) = v;
        }
    }
    __syncthreads();

    const int w  = tid >> 6;                 // wave 0..7, owns rows w*32..+31
    const int l  = tid & 63;
    const int lf = l & 15;
    const int lg = (l >> 4) & 3;
    const int bm0 = blockIdx.x * 256;
    const int rbase = bm0 + w * 32;

    f32x4 acc[2][8];
#pragma unroll
    for (int mt = 0; mt < 2; ++mt)
#pragma unroll
        for (int nt = 0; nt < 8; ++nt)
            acc[mt][nt] = (f32x4){0.f, 0.f, 0.f, 0.f};

#pragma unroll 2
    for (int k0 = 0; k0 < IN_FEATS; k0 += 32) {
        int k8 = k0 >> 3;
        // A fragments: global -> reg, inline cvt
        short8 af[2];
#pragma unroll
        for (int mt = 0; mt < 2; ++mt) {
            int grow = rbase + mt * 16 + lf;
            if (grow < M) {
                const float4* ap = (const float4*)(feat + (size_t)grow * IN_FEATS + k0 + lg * 8);
                float4 f0 = ap[0];
                float4 f1 = ap[1];
                ushort2 c0 = f2bfu2(f0.x, f0.y);
                ushort2 c1 = f2bfu2(f0.z, f0.w);
                ushort2 c2 = f2bfu2(f1.x, f1.y);
                ushort2 c3 = f2bfu2(f1.z, f1.w);
                af[mt] = (short8){ (short)c0.x, (short)c0.y, (short)c1.x, (short)c1.y,
                                   (short)c2.x, (short)c2.y, (short)c3.x, (short)c3.y };
            } else {
                af[mt] = (short8){ 0, 0, 0, 0, 0, 0, 0, 0 };
            }
        }
        // B fragments from LDS (swizzled), 2 n-halves to bound registers
#pragma unroll
        for (int nh = 0; nh < 2; ++nh) {
            short8 bf[4];
#pragma unroll
            for (int q = 0; q < 4; ++q) {
                int nt = nh * 4 + q;
                int n = nt * 16 + lf;
                int g = (k8 + lg) ^ (lf & 7);
                bf[q] = *(const short8*)(Bl + n * IN_FEATS + g * 8);
            }
#pragma unroll
            for (int q = 0; q < 4; ++q) {
                int nt = nh * 4 + q;
                acc[0][nt] = __builtin_amdgcn_mfma_f32_16x16x32_bf16(af[0], bf[q], acc[0][nt], 0, 0, 0);
                acc[1][nt] = __builtin_amdgcn_mfma_f32_16x16x32_bf16(af[1], bf[q], acc[1][nt], 0, 0, 0);
            }
        }
    }

    // ---- epilogue: reuse LDS (B dead) for row-major transpose, coalesced stores ----
    __syncthreads();                          // all waves done reading B
    unsigned short* ep = (unsigned short*)smem_raw;   // [256 rows][128 cols]
#pragma unroll
    for (int mt = 0; mt < 2; ++mt)
#pragma unroll
        for (int nt = 0; nt < 8; ++nt)
#pragma unroll
            for (int r = 0; r < 4; ++r) {
                int row = w * 32 + mt * 16 + lg * 4 + r;
                ep[row * 128 + nt * 16 + lf] = f2bfu(acc[mt][nt][r]);
            }
    __syncthreads();
#pragma unroll
    for (int i = 0; i < 8; ++i) {
        int lrow = w * 32 + i * 4 + (l >> 4);
        ushort8 v = *(const ushort8*)(ep + lrow * 128 + (l & 15) * 8);
        int grow = bm0 + lrow;
        if (grow < M)
            *(ushort8*)(hself16 + (size_t)grow * OUT_FEATS + (l & 15) * 8) = v;
    }
}

// ---------------- K5: per-bucket LDS counting sort + fused gather/finalize ----------------
// 512 threads / 8 waves per block: NB=782 blocks was grid-capping occupancy.
__global__ __launch_bounds__(512, 8) void sort_gather(
    const int* __restrict__ bucket_base, const int* __restrict__ bucket_total,
    const int* __restrict__ bedges, const unsigned short* __restrict__ hself16,
    float* __restrict__ out)
{
    __shared__ int sorted[BCAP];
    __shared__ int cnt[128], off[128], cursor[128], sd[128];

    int b = blockIdx.x, t = threadIdx.x;
    int base = bucket_base[b];
    int tot = bucket_total[b];
    if (tot > BCAP) tot = BCAP;
    int nnodes = NUM_NODES - b * 128;
    if (nnodes > 128) nnodes = 128;

    if (t < 128) cnt[t] = 0;
    __syncthreads();
    for (int i = t; i < tot; i += 512)
        atomicAdd(&cnt[bedges[base + i] >> 17], 1);
    __syncthreads();
    if (t < 128) sd[t] = cnt[t];
    __syncthreads();
    for (int o = 1; o < 128; o <<= 1) {
        int x = 0;
        if (t < 128 && t >= o) x = sd[t - o];
        __syncthreads();
        if (t < 128) sd[t] += x;
        __syncthreads();
    }
    if (t < 128) { int e = sd[t] - cnt[t]; off[t] = e; cursor[t] = e; }
    __syncthreads();
    for (int i = t; i < tot; i += 512) {
        int e = bedges[base + i];           // re-read (L2-hot)
        int r = atomicAdd(&cursor[e >> 17], 1);
        sorted[r] = e & 0x1FFFF;
    }
    __syncthreads();

    // gather: 8 waves; wave w handles local nodes w, w+8, ...; 16 edges in flight
    int w = t >> 6, l = t & 63, lg = l >> 4, lf = l & 15;
    for (int ln = w; ln < nnodes; ln += 8) {
        int beg = off[ln];
        int end = beg + cnt[ln];
        float acc[8];
#pragma unroll
        for (int i = 0; i < 8; ++i) acc[i] = 0.f;
        for (int j0 = beg; j0 < end; j0 += 16) {
            int  jj[4];
            bool pp[4];
            int  ss[4];
#pragma unroll
            for (int q = 0; q < 4; ++q) {
                jj[q] = j0 + q * 4 + lg;
                pp[q] = jj[q] < end;
                ss[q] = pp[q] ? sorted[jj[q]] : 0;
            }
            ushort8 h[4];
#pragma unroll
            for (int q = 0; q < 4; ++q)
                h[q] = *(const ushort8*)(hself16 + (size_t)ss[q] * OUT_FEATS + lf * 8);
#pragma unroll
            for (int q = 0; q < 4; ++q)
                if (pp[q]) {
#pragma unroll
                    for (int i = 0; i < 8; ++i) acc[i] += bf2f(h[q][i]);
                }
        }
#pragma unroll
        for (int i = 0; i < 8; ++i) {
            acc[i] += __shfl_xor(acc[i], 16, 64);
            acc[i] += __shfl_xor(acc[i], 32, 64);
        }
        if (lg == 0) {
            int n = b * 128 + ln;
            float inv = 1.0f / (float)(end - beg + 1);
            ushort8 hs = *(const ushort8*)(hself16 + (size_t)n * OUT_FEATS + lf * 8);
            float v[8];
#pragma unroll
            for (int i = 0; i < 8; ++i)
                v[i] = fmaxf((acc[i] + bf2f(hs[i])) * inv, 0.f);
            float4* op = (float4*)(out + (size_t)n * OUT_FEATS + lf * 8);
            op[0] = make_float4(v[0], v[1], v[2], v[3]);
            op[1] = make_float4(v[4], v[5], v[6], v[7]);
        }
    }
}

extern "C" void kernel_launch(void* const* d_in, const int* in_sizes, int n_in,
                              void* d_out, int out_size, void* d_ws, size_t ws_size,
                              hipStream_t stream) {
    const float* feat = (const float*)d_in[0];
    const float* W    = (const float*)d_in[1];
    const int*   src  = (const int*)d_in[2];
    const int*   dst  = (const int*)d_in[3];
    float* out = (float*)d_out;

    char* ws = (char*)d_ws;
    unsigned short* hself16 = (unsigned short*)ws;                 // 25,600,000 B
    unsigned short* Wt      = (unsigned short*)(ws + 25600000);    //     65,536 B
    int* counts       = (int*)(ws + 25665536);                     //    400,384 B
    int* bucket_total = (int*)(ws + 26065920);                     //      3,200 B
    int* bucket_base  = (int*)(ws + 26069120);                     //      3,200 B
    int* bedges       = (int*)(ws + 26072320);                     //  6,400,000 B

    convert_hist<<<256, 256, 0, stream>>>(W, Wt, dst, counts);
    scan_chunks<<<NB, 128, 0, stream>>>(counts, bucket_total);
    scan_buckets<<<1, 256, 0, stream>>>(bucket_total, bucket_base);
    gemm_scatter<<<GEMM_BLOCKS + EC, 512, 0, stream>>>(
        feat, Wt, hself16, NUM_NODES, src, dst, counts, bucket_base, bedges);
    sort_gather<<<NB, 512, 0, stream>>>(bucket_base, bucket_total, bedges, hself16, out);
}